// Round 1
// baseline (531.686 us; speedup 1.0000x reference)
//
#include <hip/hip_runtime.h>
#include <stdint.h>

#define QL 2048
#define NHEAD 16
#define DHEAD 64
#define DMODEL 1024
#define DINNER 4096

typedef __attribute__((ext_vector_type(8))) short bf16x8;
typedef __attribute__((ext_vector_type(4))) float f32x4;

__device__ __forceinline__ ushort f2bf(float f) {
  uint32_t u = __float_as_uint(f);
  u = (u + 0x7fffu + ((u >> 16) & 1u)) >> 16;
  return (ushort)u;
}

__device__ __forceinline__ void gload_lds16(const void* g, void* l) {
  auto gp = reinterpret_cast<const uint32_t __attribute__((address_space(1)))*>(
      reinterpret_cast<uintptr_t>(g));
  auto lp = reinterpret_cast<uint32_t __attribute__((address_space(3)))*>(
      (uint32_t)reinterpret_cast<uintptr_t>(l));
  __builtin_amdgcn_global_load_lds(gp, lp, 16, 0, 0);
}

// ---------------- fp32 -> bf16 conversion ----------------
__global__ __launch_bounds__(256) void cvt_bf16_k(const float* __restrict__ in,
                                                  ushort* __restrict__ out, int n4) {
  int i = blockIdx.x * 256 + threadIdx.x;
  if (i < n4) {
    float4 v = ((const float4*)in)[i];
    ushort4 u;
    u.x = f2bf(v.x); u.y = f2bf(v.y); u.z = f2bf(v.z); u.w = f2bf(v.w);
    ((ushort4*)out)[i] = u;
  }
}

// ---------------- NT GEMM: C[M,N] = A[M,K] * B[N,K]^T (bf16 in, f32 acc) ----
// 128x128 tile, BK=32, 4 waves (2x2 of 64x64), 16x16x32 bf16 MFMA (m97 structure)
#define EPI_QKV 0
#define EPI_RK 1
#define EPI_F32 2
#define EPI_RELU_BF16 3
#define EPI_BIAS_F32 4

template <int EPI>
__global__ __launch_bounds__(256) void gemm_nt(
    const ushort* __restrict__ A, const ushort* __restrict__ B, int M, int N, int K,
    float* __restrict__ Cf, ushort* __restrict__ Cb, const float* __restrict__ bias,
    ushort* __restrict__ qw, ushort* __restrict__ qr, ushort* __restrict__ kbuf,
    ushort* __restrict__ vt, const float* __restrict__ rwb, const float* __restrict__ rrb) {
  __shared__ ushort As[128 * 32];
  __shared__ ushort Bs[128 * 32];
  const int t = threadIdx.x;
  const int lane = t & 63, wv = t >> 6;
  const int wr = wv >> 1, wc = wv & 1;
  const int m0 = blockIdx.y * 128, n0 = blockIdx.x * 128;
  const int rif = lane & 15;
  const int kb = (lane >> 4) * 16;  // byte offset of this lane's k-chunk (8 bf16)

  f32x4 acc[4][4] = {};
  const char* Ab = (const char*)A;
  const char* Bb = (const char*)B;
  const int arow = t >> 2;          // 0..63
  const int acol = (t & 3) * 16;    // byte within the 64B k-row

  for (int k0 = 0; k0 < K; k0 += 32) {
    __syncthreads();
    {
      size_t abase = ((size_t)(m0 + arow) * K + k0) * 2 + acol;
      gload_lds16(Ab + abase, (char*)As + t * 16);
      gload_lds16(Ab + abase + (size_t)64 * K * 2, (char*)As + t * 16 + 4096);
      size_t bbase = ((size_t)(n0 + arow) * K + k0) * 2 + acol;
      gload_lds16(Bb + bbase, (char*)Bs + t * 16);
      gload_lds16(Bb + bbase + (size_t)64 * K * 2, (char*)Bs + t * 16 + 4096);
    }
    __syncthreads();
    bf16x8 af[4], bfr[4];
#pragma unroll
    for (int m = 0; m < 4; m++)
      af[m] = *(const bf16x8*)((const char*)As + (wr * 64 + m * 16 + rif) * 64 + kb);
#pragma unroll
    for (int n = 0; n < 4; n++)
      bfr[n] = *(const bf16x8*)((const char*)Bs + (wc * 64 + n * 16 + rif) * 64 + kb);
#pragma unroll
    for (int m = 0; m < 4; m++)
#pragma unroll
      for (int n = 0; n < 4; n++)
        acc[m][n] = __builtin_amdgcn_mfma_f32_16x16x32_bf16(af[m], bfr[n], acc[m][n], 0, 0, 0);
  }

  const int rbase = (lane >> 4) * 4;
#pragma unroll
  for (int m = 0; m < 4; m++) {
#pragma unroll
    for (int n = 0; n < 4; n++) {
#pragma unroll
      for (int reg = 0; reg < 4; reg++) {
        int gr = m0 + wr * 64 + m * 16 + rbase + reg;
        int gc = n0 + wc * 64 + n * 16 + (lane & 15);
        float v = acc[m][n][reg];
        if (EPI == EPI_F32) {
          Cf[(size_t)gr * N + gc] = v;
        } else if (EPI == EPI_BIAS_F32) {
          Cf[(size_t)gr * N + gc] = v + bias[gc];
        } else if (EPI == EPI_RELU_BF16) {
          Cb[(size_t)gr * N + gc] = f2bf(fmaxf(v + bias[gc], 0.f));
        } else if (EPI == EPI_RK) {
          int hn = gc >> 6, hd = gc & 63;
          Cb[((size_t)hn * QL + gr) * 64 + hd] = f2bf(v);
        } else {  // EPI_QKV : rows are (i*2+b), cols h in [0,3072)
          int which = gc >> 10, hh = gc & 1023;
          int hn = hh >> 6, hd = hh & 63;
          int qi = gr >> 1, qb = gr & 1;
          size_t off = ((size_t)(qb * NHEAD + hn) * QL + qi) * 64 + hd;
          if (which == 0) {
            qw[off] = f2bf(v + rwb[hh]);
            qr[off] = f2bf(v + rrb[hh]);
          } else if (which == 1) {
            kbuf[off] = f2bf(v);
          } else {  // V transposed: [bn][d][q]
            vt[((size_t)(qb * NHEAD + hn) * 64 + hd) * QL + qi] = f2bf(v);
          }
        }
      }
    }
  }
}

// ---------------- fused causal attention with TXL rel-shift ----------------
// block: (i-tile of 64 rows) x (b*16+n). 4 waves, each owns 16 rows.
// BD_shifted[i,j] = Qr[i] . rk[j + QL-1 - i]  (valid for j<=i; j>i masked)
__global__ __launch_bounds__(256) void flash_attn(
    const ushort* __restrict__ Qw, const ushort* __restrict__ Qr,
    const ushort* __restrict__ Kb, const ushort* __restrict__ Vt,
    const ushort* __restrict__ Rk, ushort* __restrict__ out) {
  __shared__ ushort K_lds[64 * 64];
  __shared__ ushort V_lds[64 * 64];   // [d][j]
  __shared__ ushort R_lds[128 * 64];  // rk slice rows T0..T0+127
  __shared__ float BD_lds[4][16 * 80];
  __shared__ ushort P_lds[4][16 * 80];

  const int t = threadIdx.x;
  const int lane = t & 63, wv = t >> 6;
  const int bn = blockIdx.y;
  const int qb = bn >> 4, hn = bn & 15;
  const int i0 = (gridDim.x - 1 - blockIdx.x) * 64;  // heavy tiles first
  const int iw = i0 + wv * 16;
  const int c4 = lane & 15, g4 = lane >> 4;
  const int k8b = g4 * 16;

  const char* Qwb = (const char*)(Qw + (size_t)bn * QL * 64);
  const char* Qrb = (const char*)(Qr + (size_t)bn * QL * 64);
  const char* Kbb = (const char*)(Kb + (size_t)bn * QL * 64);
  const char* Vtb = (const char*)(Vt + (size_t)bn * 64 * QL);
  const char* Rkb = (const char*)(Rk + (size_t)hn * QL * 64);

  bf16x8 qwf[2], qrf[2];
#pragma unroll
  for (int kk = 0; kk < 2; kk++) {
    qwf[kk] = *(const bf16x8*)(Qwb + (size_t)(iw + c4) * 128 + kk * 64 + k8b);
    qrf[kk] = *(const bf16x8*)(Qrb + (size_t)(iw + c4) * 128 + kk * 64 + k8b);
  }

  f32x4 o_acc[4] = {};
  float m_run[4], l_run[4];
#pragma unroll
  for (int r = 0; r < 4; r++) { m_run[r] = -3.0e38f; l_run[r] = 0.f; }

  for (int j0 = 0; j0 <= i0; j0 += 64) {
    __syncthreads();
    const int T0 = j0 - i0 + (QL - 64);
#pragma unroll
    for (int p = 0; p < 2; p++) {
      int o = t * 16 + p * 4096;
      gload_lds16(Kbb + (size_t)(j0 + (o >> 7)) * 128 + (o & 127), (char*)K_lds + o);
      gload_lds16(Vtb + (size_t)(o >> 7) * (QL * 2) + j0 * 2 + (o & 127), (char*)V_lds + o);
    }
#pragma unroll
    for (int p = 0; p < 4; p++) {
      int o = t * 16 + p * 4096;
      int srow = T0 + (o >> 7);
      srow = srow > QL - 1 ? QL - 1 : srow;  // clamped rows feed masked cells only
      gload_lds16(Rkb + (size_t)srow * 128 + (o & 127), (char*)R_lds + o);
    }
    __syncthreads();

    f32x4 acc_s[4] = {};
    f32x4 acc_bd[5] = {};
    const int baseloc = 48 - wv * 16;
#pragma unroll
    for (int kk = 0; kk < 2; kk++) {
#pragma unroll
      for (int nf = 0; nf < 4; nf++) {
        bf16x8 bk = *(const bf16x8*)((const char*)K_lds + (nf * 16 + c4) * 128 + kk * 64 + k8b);
        acc_s[nf] = __builtin_amdgcn_mfma_f32_16x16x32_bf16(qwf[kk], bk, acc_s[nf], 0, 0, 0);
      }
#pragma unroll
      for (int tf = 0; tf < 5; tf++) {
        bf16x8 br = *(const bf16x8*)((const char*)R_lds + (baseloc + tf * 16 + c4) * 128 + kk * 64 + k8b);
        acc_bd[tf] = __builtin_amdgcn_mfma_f32_16x16x32_bf16(qrf[kk], br, acc_bd[tf], 0, 0, 0);
      }
    }
    // BD' (D-layout) -> LDS so each lane can gather its shifted element
#pragma unroll
    for (int tf = 0; tf < 5; tf++)
#pragma unroll
      for (int reg = 0; reg < 4; reg++)
        BD_lds[wv][(g4 * 4 + reg) * 80 + tf * 16 + c4] = acc_bd[tf][reg];

    float sv[4][4];
    float rowmax[4] = {-3.0e38f, -3.0e38f, -3.0e38f, -3.0e38f};
#pragma unroll
    for (int nf = 0; nf < 4; nf++) {
#pragma unroll
      for (int reg = 0; reg < 4; reg++) {
        int rr = g4 * 4 + reg;
        int jg = j0 + nf * 16 + c4;
        int ig = iw + rr;
        int bdt = nf * 16 + c4 + 15 - rr;  // in [0,78]
        float v = (acc_s[nf][reg] + BD_lds[wv][rr * 80 + bdt]) * 0.125f;
        v = (jg <= ig) ? v : -3.0e38f;
        sv[nf][reg] = v;
        rowmax[reg] = fmaxf(rowmax[reg], v);
      }
    }
#pragma unroll
    for (int reg = 0; reg < 4; reg++) {
      float rm = rowmax[reg];
      rm = fmaxf(rm, __shfl_xor(rm, 1));
      rm = fmaxf(rm, __shfl_xor(rm, 2));
      rm = fmaxf(rm, __shfl_xor(rm, 4));
      rm = fmaxf(rm, __shfl_xor(rm, 8));
      float mnew = fmaxf(m_run[reg], rm);
      float alpha = __expf(m_run[reg] - mnew);
      float rsum = 0.f;
#pragma unroll
      for (int nf = 0; nf < 4; nf++) {
        float p = __expf(sv[nf][reg] - mnew);
        sv[nf][reg] = p;
        rsum += p;
      }
      rsum += __shfl_xor(rsum, 1);
      rsum += __shfl_xor(rsum, 2);
      rsum += __shfl_xor(rsum, 4);
      rsum += __shfl_xor(rsum, 8);
      l_run[reg] = l_run[reg] * alpha + rsum;
      m_run[reg] = mnew;
#pragma unroll
      for (int df = 0; df < 4; df++) o_acc[df][reg] *= alpha;
    }
    // P (D-layout) -> LDS -> A-fragment layout
#pragma unroll
    for (int nf = 0; nf < 4; nf++)
#pragma unroll
      for (int reg = 0; reg < 4; reg++)
        P_lds[wv][(g4 * 4 + reg) * 80 + nf * 16 + c4] = f2bf(sv[nf][reg]);
#pragma unroll
    for (int kk = 0; kk < 2; kk++) {
      bf16x8 pa = *(const bf16x8*)((const char*)P_lds[wv] + c4 * 160 + kk * 64 + k8b);
#pragma unroll
      for (int df = 0; df < 4; df++) {
        bf16x8 bv = *(const bf16x8*)((const char*)V_lds + (df * 16 + c4) * 128 + kk * 64 + k8b);
        o_acc[df] = __builtin_amdgcn_mfma_f32_16x16x32_bf16(pa, bv, o_acc[df], 0, 0, 0);
      }
    }
  }

#pragma unroll
  for (int reg = 0; reg < 4; reg++) {
    float inv = 1.0f / l_run[reg];
    int ig = iw + g4 * 4 + reg;
    size_t grow = (size_t)(ig * 2 + qb) * 1024 + hn * 64;
#pragma unroll
    for (int df = 0; df < 4; df++)
      out[grow + df * 16 + c4] = f2bf(o_acc[df][reg] * inv);
  }
}

// ---------------- residual + LayerNorm ----------------
template <bool WB>
__global__ __launch_bounds__(256) void ln_res(
    const float* __restrict__ xa, const float* __restrict__ xb,
    const float* __restrict__ g, const float* __restrict__ bt,
    float* __restrict__ of, ushort* __restrict__ ob) {
  __shared__ float red[8];
  const int row = blockIdx.x;
  const int t = threadIdx.x;
  const int lane = t & 63, wv = t >> 6;
  const float4 a = *(const float4*)(xa + (size_t)row * 1024 + t * 4);
  const float4 c = *(const float4*)(xb + (size_t)row * 1024 + t * 4);
  float x[4] = {a.x + c.x, a.y + c.y, a.z + c.z, a.w + c.w};
  float s = x[0] + x[1] + x[2] + x[3];
  for (int m = 1; m < 64; m <<= 1) s += __shfl_xor(s, m);
  if (lane == 0) red[wv] = s;
  __syncthreads();
  float mu = (red[0] + red[1] + red[2] + red[3]) * (1.f / 1024.f);
  float d[4];
  float ss = 0.f;
#pragma unroll
  for (int i = 0; i < 4; i++) { d[i] = x[i] - mu; ss += d[i] * d[i]; }
  for (int m = 1; m < 64; m <<= 1) ss += __shfl_xor(ss, m);
  if (lane == 0) red[4 + wv] = ss;
  __syncthreads();
  float var = (red[4] + red[5] + red[6] + red[7]) * (1.f / 1024.f);
  float rs = rsqrtf(var + 1e-5f);
  float4 gv = *(const float4*)(g + t * 4);
  float4 bv = *(const float4*)(bt + t * 4);
  float y[4] = {d[0] * rs * gv.x + bv.x, d[1] * rs * gv.y + bv.y,
                d[2] * rs * gv.z + bv.z, d[3] * rs * gv.w + bv.w};
  float4 yo = make_float4(y[0], y[1], y[2], y[3]);
  *(float4*)(of + (size_t)row * 1024 + t * 4) = yo;
  if (WB) {
    ushort4 u;
    u.x = f2bf(y[0]); u.y = f2bf(y[1]); u.z = f2bf(y[2]); u.w = f2bf(y[3]);
    *(ushort4*)(ob + (size_t)row * 1024 + t * 4) = u;
  }
}

// ---------------- host orchestration ----------------
extern "C" void kernel_launch(void* const* d_in, const int* in_sizes, int n_in,
                              void* d_out, int out_size, void* d_ws, size_t ws_size,
                              hipStream_t stream) {
  const float* dec_inp = (const float*)d_in[0];
  const float* r_in = (const float*)d_in[1];
  const float* rwb = (const float*)d_in[2];
  const float* rrb = (const float*)d_in[3];
  const float* qkv_w = (const float*)d_in[4];
  const float* rnet_w = (const float*)d_in[5];
  const float* o_w = (const float*)d_in[6];
  const float* ln_attn_g = (const float*)d_in[7];
  const float* ln_attn_b = (const float*)d_in[8];
  const float* w1 = (const float*)d_in[9];
  const float* b1 = (const float*)d_in[10];
  const float* w2 = (const float*)d_in[11];
  const float* b2 = (const float*)d_in[12];
  const float* ln_ff_g = (const float*)d_in[13];
  const float* ln_ff_b = (const float*)d_in[14];
  float* out = (float*)d_out;

  char* ws = (char*)d_ws;
  size_t off = 0;
  auto alloc = [&](size_t bytes) {
    char* p = ws + off;
    off += (bytes + 255) & ~(size_t)255;
    return p;
  };
  const int ROWS = QL * 2;  // 4096 (i*2+b)
  ushort* qkvw_b = (ushort*)alloc((size_t)3072 * 1024 * 2);
  ushort* rnetw_b = (ushort*)alloc((size_t)1024 * 1024 * 2);
  ushort* ow_b = (ushort*)alloc((size_t)1024 * 1024 * 2);
  ushort* w1_b = (ushort*)alloc((size_t)4096 * 1024 * 2);
  ushort* w2_b = (ushort*)alloc((size_t)1024 * 4096 * 2);
  ushort* x_b = (ushort*)alloc((size_t)ROWS * 1024 * 2);
  ushort* r_b = (ushort*)alloc((size_t)QL * 1024 * 2);
  ushort* Qw = (ushort*)alloc((size_t)32 * QL * 64 * 2);
  ushort* Qr = (ushort*)alloc((size_t)32 * QL * 64 * 2);
  ushort* Kb = (ushort*)alloc((size_t)32 * QL * 64 * 2);
  ushort* Vt = (ushort*)alloc((size_t)32 * 64 * QL * 2);
  ushort* rk = (ushort*)alloc((size_t)16 * QL * 64 * 2);
  ushort* avec = (ushort*)alloc((size_t)ROWS * 1024 * 2);
  float* attn_out = (float*)alloc((size_t)ROWS * 1024 * 4);
  float* x1f = (float*)alloc((size_t)ROWS * 1024 * 4);
  ushort* x1b = (ushort*)alloc((size_t)ROWS * 1024 * 2);
  ushort* hidden = (ushort*)alloc((size_t)ROWS * 4096 * 2);
  float* core = (float*)alloc((size_t)ROWS * 1024 * 4);

  auto cvt = [&](const float* src, ushort* dst, int n) {
    int n4 = n / 4;
    cvt_bf16_k<<<n4 / 256, 256, 0, stream>>>(src, dst, n4);
  };
  cvt(qkv_w, qkvw_b, 3072 * 1024);
  cvt(rnet_w, rnetw_b, 1024 * 1024);
  cvt(o_w, ow_b, 1024 * 1024);
  cvt(w1, w1_b, 4096 * 1024);
  cvt(w2, w2_b, 1024 * 4096);
  cvt(dec_inp, x_b, ROWS * 1024);
  cvt(r_in, r_b, QL * 1024);

  // QKV projection: [4096,1024] x [3072,1024]^T
  gemm_nt<EPI_QKV><<<dim3(3072 / 128, ROWS / 128), 256, 0, stream>>>(
      x_b, qkvw_b, ROWS, 3072, 1024, nullptr, nullptr, nullptr, Qw, Qr, Kb, Vt, rwb, rrb);
  // r_head_k: [2048,1024] x [1024,1024]^T
  gemm_nt<EPI_RK><<<dim3(1024 / 128, QL / 128), 256, 0, stream>>>(
      r_b, rnetw_b, QL, 1024, 1024, nullptr, rk, nullptr, nullptr, nullptr, nullptr, nullptr,
      nullptr, nullptr);
  // fused causal attention
  flash_attn<<<dim3(QL / 64, 32), 256, 0, stream>>>(Qw, Qr, Kb, Vt, rk, avec);
  // output projection
  gemm_nt<EPI_F32><<<dim3(1024 / 128, ROWS / 128), 256, 0, stream>>>(
      avec, ow_b, ROWS, 1024, 1024, attn_out, nullptr, nullptr, nullptr, nullptr, nullptr,
      nullptr, nullptr, nullptr);
  // post-LN 1 (residual = dec_inp)
  ln_res<true><<<ROWS, 256, 0, stream>>>(dec_inp, attn_out, ln_attn_g, ln_attn_b, x1f, x1b);
  // FFN1 + bias + relu
  gemm_nt<EPI_RELU_BF16><<<dim3(4096 / 128, ROWS / 128), 256, 0, stream>>>(
      x1b, w1_b, ROWS, 4096, 1024, nullptr, hidden, b1, nullptr, nullptr, nullptr, nullptr,
      nullptr, nullptr);
  // FFN2 + bias
  gemm_nt<EPI_BIAS_F32><<<dim3(1024 / 128, ROWS / 128), 256, 0, stream>>>(
      hidden, w2_b, ROWS, 1024, 4096, core, nullptr, b2, nullptr, nullptr, nullptr, nullptr,
      nullptr, nullptr);
  // post-LN 2 -> final output
  ln_res<false><<<ROWS, 256, 0, stream>>>(x1f, core, ln_ff_g, ln_ff_b, out, nullptr);
}

// Round 3
// 501.314 us; speedup vs baseline: 1.0606x; 1.0606x over previous
//
#include <hip/hip_runtime.h>
#include <stdint.h>

#define QL 2048
#define NHEAD 16
#define DHEAD 64
#define DMODEL 1024
#define DINNER 4096

typedef __attribute__((ext_vector_type(8))) short bf16x8;
typedef __attribute__((ext_vector_type(4))) float f32x4;

__device__ __forceinline__ ushort f2bf(float f) {
  uint32_t u = __float_as_uint(f);
  u = (u + 0x7fffu + ((u >> 16) & 1u)) >> 16;
  return (ushort)u;
}
__device__ __forceinline__ float bf2f(ushort u) {
  return __uint_as_float(((uint32_t)u) << 16);
}

__device__ __forceinline__ void gload_lds16(const void* g, void* l) {
  auto gp = reinterpret_cast<const uint32_t __attribute__((address_space(1)))*>(
      reinterpret_cast<uintptr_t>(g));
  auto lp = reinterpret_cast<uint32_t __attribute__((address_space(3)))*>(
      (uint32_t)reinterpret_cast<uintptr_t>(l));
  __builtin_amdgcn_global_load_lds(gp, lp, 16, 0, 0);
}

// ---------------- fp32 -> bf16 conversion ----------------
__global__ __launch_bounds__(256) void cvt_bf16_k(const float* __restrict__ in,
                                                  ushort* __restrict__ out, int n4) {
  int i = blockIdx.x * 256 + threadIdx.x;
  if (i < n4) {
    float4 v = ((const float4*)in)[i];
    ushort4 u;
    u.x = f2bf(v.x); u.y = f2bf(v.y); u.z = f2bf(v.z); u.w = f2bf(v.w);
    ((ushort4*)out)[i] = u;
  }
}

// ---------------- NT GEMM: C[M,N] = A[M,K] * B[N,K]^T (bf16 in, f32 acc) ----
#define EPI_QKV 0
#define EPI_RK 1
#define EPI_F32 2
#define EPI_RELU_BF16 3
#define EPI_BIAS_F32 4

template <int EPI>
__global__ __launch_bounds__(256) void gemm_nt(
    const ushort* __restrict__ A, const ushort* __restrict__ B, int M, int N, int K,
    float* __restrict__ Cf, ushort* __restrict__ Cb, const float* __restrict__ bias,
    ushort* __restrict__ qw, ushort* __restrict__ qr, ushort* __restrict__ kbuf,
    ushort* __restrict__ vt, const float* __restrict__ rwb, const float* __restrict__ rrb) {
  __shared__ ushort As[128 * 32];
  __shared__ ushort Bs[128 * 32];
  const int t = threadIdx.x;
  const int lane = t & 63, wv = t >> 6;
  const int wr = wv >> 1, wc = wv & 1;
  const int m0 = blockIdx.y * 128, n0 = blockIdx.x * 128;
  const int rif = lane & 15;
  const int kb = (lane >> 4) * 16;

  f32x4 acc[4][4] = {};
  const char* Ab = (const char*)A;
  const char* Bb = (const char*)B;
  const int arow = t >> 2;
  const int acol = (t & 3) * 16;

  for (int k0 = 0; k0 < K; k0 += 32) {
    __syncthreads();
    {
      size_t abase = ((size_t)(m0 + arow) * K + k0) * 2 + acol;
      gload_lds16(Ab + abase, (char*)As + t * 16);
      gload_lds16(Ab + abase + (size_t)64 * K * 2, (char*)As + t * 16 + 4096);
      size_t bbase = ((size_t)(n0 + arow) * K + k0) * 2 + acol;
      gload_lds16(Bb + bbase, (char*)Bs + t * 16);
      gload_lds16(Bb + bbase + (size_t)64 * K * 2, (char*)Bs + t * 16 + 4096);
    }
    __syncthreads();
    bf16x8 af[4], bfr[4];
#pragma unroll
    for (int m = 0; m < 4; m++)
      af[m] = *(const bf16x8*)((const char*)As + (wr * 64 + m * 16 + rif) * 64 + kb);
#pragma unroll
    for (int n = 0; n < 4; n++)
      bfr[n] = *(const bf16x8*)((const char*)Bs + (wc * 64 + n * 16 + rif) * 64 + kb);
#pragma unroll
    for (int m = 0; m < 4; m++)
#pragma unroll
      for (int n = 0; n < 4; n++)
        acc[m][n] = __builtin_amdgcn_mfma_f32_16x16x32_bf16(af[m], bfr[n], acc[m][n], 0, 0, 0);
  }

  const int rbase = (lane >> 4) * 4;
#pragma unroll
  for (int m = 0; m < 4; m++) {
#pragma unroll
    for (int n = 0; n < 4; n++) {
#pragma unroll
      for (int reg = 0; reg < 4; reg++) {
        int gr = m0 + wr * 64 + m * 16 + rbase + reg;
        int gc = n0 + wc * 64 + n * 16 + (lane & 15);
        float v = acc[m][n][reg];
        if (EPI == EPI_F32) {
          Cf[(size_t)gr * N + gc] = v;
        } else if (EPI == EPI_BIAS_F32) {
          Cf[(size_t)gr * N + gc] = v + bias[gc];
        } else if (EPI == EPI_RELU_BF16) {
          Cb[(size_t)gr * N + gc] = f2bf(fmaxf(v + bias[gc], 0.f));
        } else if (EPI == EPI_RK) {
          int hn = gc >> 6, hd = gc & 63;
          Cb[((size_t)hn * QL + gr) * 64 + hd] = f2bf(v);
        } else {  // EPI_QKV
          int which = gc >> 10, hh = gc & 1023;
          int hn = hh >> 6, hd = hh & 63;
          int qi = gr >> 1, qb = gr & 1;
          size_t off = ((size_t)(qb * NHEAD + hn) * QL + qi) * 64 + hd;
          if (which == 0) {
            qw[off] = f2bf(v + rwb[hh]);
            qr[off] = f2bf(v + rrb[hh]);
          } else if (which == 1) {
            kbuf[off] = f2bf(v);
          } else {
            vt[((size_t)(qb * NHEAD + hn) * 64 + hd) * QL + qi] = f2bf(v);
          }
        }
      }
    }
  }
}

// ---------------- fused causal attention with TXL rel-shift ----------------
// R1-proven structure (full restage per j-tile, separate BD/P buffers).
// New vs R1: both-sides XOR swizzle on K/V/R (bank conflicts), BD stored bf16,
// P stride 68 -> LDS 50.75KB = 3 blocks/CU, setprio around MFMA clusters.
__global__ __launch_bounds__(256) void flash_attn(
    const ushort* __restrict__ Qw, const ushort* __restrict__ Qr,
    const ushort* __restrict__ Kb, const ushort* __restrict__ Vt,
    const ushort* __restrict__ Rk, ushort* __restrict__ out) {
  __shared__ ushort K_lds[64 * 64];
  __shared__ ushort V_lds[64 * 64];   // [d][j], swizzled
  __shared__ ushort R_lds[128 * 64];  // rows T0..T0+127, swizzled
  __shared__ ushort BD_l[4][16 * 82]; // per-wave BD' (bf16)
  __shared__ ushort P_l[4][16 * 68];  // per-wave P (bf16)

  const int t = threadIdx.x;
  const int lane = t & 63, wv = t >> 6;
  const int bn = blockIdx.y;
  const int qb = bn >> 4, hn = bn & 15;
  const int i0 = (gridDim.x - 1 - blockIdx.x) * 64;  // heavy tiles first
  const int iw = i0 + wv * 16;
  const int c4 = lane & 15, g4 = lane >> 4;

  const char* Qwb = (const char*)(Qw + (size_t)bn * QL * 64);
  const char* Qrb = (const char*)(Qr + (size_t)bn * QL * 64);
  const char* Kbb = (const char*)(Kb + (size_t)bn * QL * 64);
  const char* Vtb = (const char*)(Vt + (size_t)bn * 64 * QL);
  const char* Rkb = (const char*)(Rk + (size_t)hn * QL * 64);
  ushort* bd = BD_l[wv];
  ushort* pw = P_l[wv];

  bf16x8 qwf[2], qrf[2];
#pragma unroll
  for (int kk = 0; kk < 2; kk++) {
    qwf[kk] = *(const bf16x8*)(Qwb + (size_t)(iw + c4) * 128 + kk * 64 + g4 * 16);
    qrf[kk] = *(const bf16x8*)(Qrb + (size_t)(iw + c4) * 128 + kk * 64 + g4 * 16);
  }

  f32x4 o_acc[4] = {};
  float m_run[4], l_run[4];
#pragma unroll
  for (int r = 0; r < 4; r++) { m_run[r] = -3.0e38f; l_run[r] = 0.f; }

  for (int j0 = 0; j0 <= i0; j0 += 64) {
    const int T0 = j0 - i0 + (QL - 64);
    __syncthreads();
    // --- stage K, V (8KB each); global source pre-swizzled, linear LDS dest
#pragma unroll
    for (int p = 0; p < 2; p++) {
      int o = t * 16 + p * 4096;
      int row = o >> 7, ch16 = ((((o & 127) >> 4) ^ (row & 7)) << 4);
      gload_lds16(Kbb + (size_t)(j0 + row) * 128 + ch16, (char*)K_lds + o);
      gload_lds16(Vtb + (size_t)row * (QL * 2) + (size_t)j0 * 2 + ch16, (char*)V_lds + o);
    }
    // --- stage R (16KB, rows T0..T0+127 clamped)
#pragma unroll
    for (int p = 0; p < 4; p++) {
      int o = t * 16 + p * 4096;
      int r = o >> 7;
      int srow = T0 + r; srow = srow > QL - 1 ? QL - 1 : srow;  // masked cells only
      int ch16 = ((((o & 127) >> 4) ^ (r & 7)) << 4);
      gload_lds16(Rkb + (size_t)srow * 128 + ch16, (char*)R_lds + o);
    }
    __syncthreads();

    f32x4 acc_s[4] = {};
    f32x4 acc_bd[5] = {};
    const int baseloc = 48 - wv * 16;
    __builtin_amdgcn_s_setprio(1);
#pragma unroll
    for (int kk = 0; kk < 2; kk++) {
      const int sw = (((kk * 4 + g4) ^ (c4 & 7)) << 4);
#pragma unroll
      for (int nf = 0; nf < 4; nf++) {
        bf16x8 bk = *(const bf16x8*)((const char*)K_lds + (nf * 16 + c4) * 128 + sw);
        acc_s[nf] = __builtin_amdgcn_mfma_f32_16x16x32_bf16(qwf[kk], bk, acc_s[nf], 0, 0, 0);
      }
#pragma unroll
      for (int tf = 0; tf < 5; tf++) {
        int oo = baseloc + tf * 16 + c4;  // oo&7 == c4&7
        bf16x8 br = *(const bf16x8*)((const char*)R_lds + oo * 128 + sw);
        acc_bd[tf] = __builtin_amdgcn_mfma_f32_16x16x32_bf16(qrf[kk], br, acc_bd[tf], 0, 0, 0);
      }
    }
    __builtin_amdgcn_s_setprio(0);

    // BD' (D-layout) -> per-wave LDS (bf16) for the rel-shift gather
#pragma unroll
    for (int tf = 0; tf < 5; tf++)
#pragma unroll
      for (int reg = 0; reg < 4; reg++)
        bd[(g4 * 4 + reg) * 82 + tf * 16 + c4] = f2bf(acc_bd[tf][reg]);

    float sv[4][4];
    float rowmax[4] = {-3.0e38f, -3.0e38f, -3.0e38f, -3.0e38f};
#pragma unroll
    for (int nf = 0; nf < 4; nf++) {
#pragma unroll
      for (int reg = 0; reg < 4; reg++) {
        int rr = g4 * 4 + reg;
        int jg = j0 + nf * 16 + c4;
        int ig = iw + rr;
        int bdt = nf * 16 + c4 + 15 - rr;
        float v = (acc_s[nf][reg] + bf2f(bd[rr * 82 + bdt])) * 0.125f;
        v = (jg <= ig) ? v : -3.0e38f;
        sv[nf][reg] = v;
        rowmax[reg] = fmaxf(rowmax[reg], v);
      }
    }
#pragma unroll
    for (int reg = 0; reg < 4; reg++) {
      float rm = rowmax[reg];
      rm = fmaxf(rm, __shfl_xor(rm, 1));
      rm = fmaxf(rm, __shfl_xor(rm, 2));
      rm = fmaxf(rm, __shfl_xor(rm, 4));
      rm = fmaxf(rm, __shfl_xor(rm, 8));
      float mnew = fmaxf(m_run[reg], rm);
      float alpha = __expf(m_run[reg] - mnew);
      float rsum = 0.f;
#pragma unroll
      for (int nf = 0; nf < 4; nf++) {
        float p = __expf(sv[nf][reg] - mnew);
        sv[nf][reg] = p;
        rsum += p;
      }
      rsum += __shfl_xor(rsum, 1);
      rsum += __shfl_xor(rsum, 2);
      rsum += __shfl_xor(rsum, 4);
      rsum += __shfl_xor(rsum, 8);
      l_run[reg] = l_run[reg] * alpha + rsum;
      m_run[reg] = mnew;
#pragma unroll
      for (int df = 0; df < 4; df++) o_acc[df][reg] *= alpha;
    }
    // P (D-layout) -> per-wave LDS (bf16, stride 68) -> A-fragment layout
#pragma unroll
    for (int nf = 0; nf < 4; nf++)
#pragma unroll
      for (int reg = 0; reg < 4; reg++)
        pw[(g4 * 4 + reg) * 68 + nf * 16 + c4] = f2bf(sv[nf][reg]);
    __builtin_amdgcn_s_setprio(1);
#pragma unroll
    for (int kk = 0; kk < 2; kk++) {
      bf16x8 pa = *(const bf16x8*)((const char*)pw + c4 * 136 + kk * 64 + g4 * 16);
      const int sw = (((kk * 4 + g4) ^ (c4 & 7)) << 4);
#pragma unroll
      for (int df = 0; df < 4; df++) {
        bf16x8 bv = *(const bf16x8*)((const char*)V_lds + (df * 16 + c4) * 128 + sw);
        o_acc[df] = __builtin_amdgcn_mfma_f32_16x16x32_bf16(pa, bv, o_acc[df], 0, 0, 0);
      }
    }
    __builtin_amdgcn_s_setprio(0);
  }

#pragma unroll
  for (int reg = 0; reg < 4; reg++) {
    float inv = 1.0f / l_run[reg];
    int ig = iw + g4 * 4 + reg;
    size_t grow = (size_t)(ig * 2 + qb) * 1024 + hn * 64;
#pragma unroll
    for (int df = 0; df < 4; df++)
      out[grow + df * 16 + c4] = f2bf(o_acc[df][reg] * inv);
  }
}

// ---------------- residual + LayerNorm ----------------
template <bool WB>
__global__ __launch_bounds__(256) void ln_res(
    const float* __restrict__ xa, const float* __restrict__ xb,
    const float* __restrict__ g, const float* __restrict__ bt,
    float* __restrict__ of, ushort* __restrict__ ob) {
  __shared__ float red[8];
  const int row = blockIdx.x;
  const int t = threadIdx.x;
  const int lane = t & 63, wv = t >> 6;
  const float4 a = *(const float4*)(xa + (size_t)row * 1024 + t * 4);
  const float4 c = *(const float4*)(xb + (size_t)row * 1024 + t * 4);
  float x[4] = {a.x + c.x, a.y + c.y, a.z + c.z, a.w + c.w};
  float s = x[0] + x[1] + x[2] + x[3];
  for (int m = 1; m < 64; m <<= 1) s += __shfl_xor(s, m);
  if (lane == 0) red[wv] = s;
  __syncthreads();
  float mu = (red[0] + red[1] + red[2] + red[3]) * (1.f / 1024.f);
  float d[4];
  float ss = 0.f;
#pragma unroll
  for (int i = 0; i < 4; i++) { d[i] = x[i] - mu; ss += d[i] * d[i]; }
  for (int m = 1; m < 64; m <<= 1) ss += __shfl_xor(ss, m);
  if (lane == 0) red[4 + wv] = ss;
  __syncthreads();
  float var = (red[4] + red[5] + red[6] + red[7]) * (1.f / 1024.f);
  float rs = rsqrtf(var + 1e-5f);
  float4 gv = *(const float4*)(g + t * 4);
  float4 bv = *(const float4*)(bt + t * 4);
  float y[4] = {d[0] * rs * gv.x + bv.x, d[1] * rs * gv.y + bv.y,
                d[2] * rs * gv.z + bv.z, d[3] * rs * gv.w + bv.w};
  float4 yo = make_float4(y[0], y[1], y[2], y[3]);
  *(float4*)(of + (size_t)row * 1024 + t * 4) = yo;
  if (WB) {
    ushort4 u;
    u.x = f2bf(y[0]); u.y = f2bf(y[1]); u.z = f2bf(y[2]); u.w = f2bf(y[3]);
    *(ushort4*)(ob + (size_t)row * 1024 + t * 4) = u;
  }
}

// ---------------- host orchestration ----------------
extern "C" void kernel_launch(void* const* d_in, const int* in_sizes, int n_in,
                              void* d_out, int out_size, void* d_ws, size_t ws_size,
                              hipStream_t stream) {
  const float* dec_inp = (const float*)d_in[0];
  const float* r_in = (const float*)d_in[1];
  const float* rwb = (const float*)d_in[2];
  const float* rrb = (const float*)d_in[3];
  const float* qkv_w = (const float*)d_in[4];
  const float* rnet_w = (const float*)d_in[5];
  const float* o_w = (const float*)d_in[6];
  const float* ln_attn_g = (const float*)d_in[7];
  const float* ln_attn_b = (const float*)d_in[8];
  const float* w1 = (const float*)d_in[9];
  const float* b1 = (const float*)d_in[10];
  const float* w2 = (const float*)d_in[11];
  const float* b2 = (const float*)d_in[12];
  const float* ln_ff_g = (const float*)d_in[13];
  const float* ln_ff_b = (const float*)d_in[14];
  float* out = (float*)d_out;

  char* ws = (char*)d_ws;
  size_t off = 0;
  auto alloc = [&](size_t bytes) {
    char* p = ws + off;
    off += (bytes + 255) & ~(size_t)255;
    return p;
  };
  const int ROWS = QL * 2;
  ushort* qkvw_b = (ushort*)alloc((size_t)3072 * 1024 * 2);
  ushort* rnetw_b = (ushort*)alloc((size_t)1024 * 1024 * 2);
  ushort* ow_b = (ushort*)alloc((size_t)1024 * 1024 * 2);
  ushort* w1_b = (ushort*)alloc((size_t)4096 * 1024 * 2);
  ushort* w2_b = (ushort*)alloc((size_t)1024 * 4096 * 2);
  ushort* x_b = (ushort*)alloc((size_t)ROWS * 1024 * 2);
  ushort* r_b = (ushort*)alloc((size_t)QL * 1024 * 2);
  ushort* Qw = (ushort*)alloc((size_t)32 * QL * 64 * 2);
  ushort* Qr = (ushort*)alloc((size_t)32 * QL * 64 * 2);
  ushort* Kb = (ushort*)alloc((size_t)32 * QL * 64 * 2);
  ushort* Vt = (ushort*)alloc((size_t)32 * 64 * QL * 2);
  ushort* rk = (ushort*)alloc((size_t)16 * QL * 64 * 2);
  ushort* avec = (ushort*)alloc((size_t)ROWS * 1024 * 2);
  float* attn_out = (float*)alloc((size_t)ROWS * 1024 * 4);
  float* x1f = (float*)alloc((size_t)ROWS * 1024 * 4);
  ushort* x1b = (ushort*)alloc((size_t)ROWS * 1024 * 2);
  ushort* hidden = (ushort*)alloc((size_t)ROWS * 4096 * 2);
  float* core = (float*)alloc((size_t)ROWS * 1024 * 4);

  auto cvt = [&](const float* src, ushort* dst, int n) {
    int n4 = n / 4;
    cvt_bf16_k<<<n4 / 256, 256, 0, stream>>>(src, dst, n4);
  };
  cvt(qkv_w, qkvw_b, 3072 * 1024);
  cvt(rnet_w, rnetw_b, 1024 * 1024);
  cvt(o_w, ow_b, 1024 * 1024);
  cvt(w1, w1_b, 4096 * 1024);
  cvt(w2, w2_b, 1024 * 4096);
  cvt(dec_inp, x_b, ROWS * 1024);
  cvt(r_in, r_b, QL * 1024);

  gemm_nt<EPI_QKV><<<dim3(3072 / 128, ROWS / 128), 256, 0, stream>>>(
      x_b, qkvw_b, ROWS, 3072, 1024, nullptr, nullptr, nullptr, Qw, Qr, Kb, Vt, rwb, rrb);
  gemm_nt<EPI_RK><<<dim3(1024 / 128, QL / 128), 256, 0, stream>>>(
      r_b, rnetw_b, QL, 1024, 1024, nullptr, rk, nullptr, nullptr, nullptr, nullptr, nullptr,
      nullptr, nullptr);
  flash_attn<<<dim3(QL / 64, 32), 256, 0, stream>>>(Qw, Qr, Kb, Vt, rk, avec);
  gemm_nt<EPI_F32><<<dim3(1024 / 128, ROWS / 128), 256, 0, stream>>>(
      avec, ow_b, ROWS, 1024, 1024, attn_out, nullptr, nullptr, nullptr, nullptr, nullptr,
      nullptr, nullptr, nullptr);
  ln_res<true><<<ROWS, 256, 0, stream>>>(dec_inp, attn_out, ln_attn_g, ln_attn_b, x1f, x1b);
  gemm_nt<EPI_RELU_BF16><<<dim3(4096 / 128, ROWS / 128), 256, 0, stream>>>(
      x1b, w1_b, ROWS, 4096, 1024, nullptr, hidden, b1, nullptr, nullptr, nullptr, nullptr,
      nullptr, nullptr);
  gemm_nt<EPI_BIAS_F32><<<dim3(1024 / 128, ROWS / 128), 256, 0, stream>>>(
      hidden, w2_b, ROWS, 1024, 4096, core, nullptr, b2, nullptr, nullptr, nullptr, nullptr,
      nullptr, nullptr);
  ln_res<false><<<ROWS, 256, 0, stream>>>(x1f, core, ln_ff_g, ln_ff_b, out, nullptr);
}

// Round 4
// 474.962 us; speedup vs baseline: 1.1194x; 1.0555x over previous
//
#include <hip/hip_runtime.h>
#include <stdint.h>

#define QL 2048
#define NHEAD 16
#define DHEAD 64
#define DMODEL 1024
#define DINNER 4096

typedef __attribute__((ext_vector_type(8))) short bf16x8;
typedef __attribute__((ext_vector_type(4))) float f32x4;

__device__ __forceinline__ ushort f2bf(float f) {
  uint32_t u = __float_as_uint(f);
  u = (u + 0x7fffu + ((u >> 16) & 1u)) >> 16;
  return (ushort)u;
}
__device__ __forceinline__ float bf2f(ushort u) {
  return __uint_as_float(((uint32_t)u) << 16);
}

__device__ __forceinline__ void gload_lds16(const void* g, void* l) {
  auto gp = reinterpret_cast<const uint32_t __attribute__((address_space(1)))*>(
      reinterpret_cast<uintptr_t>(g));
  auto lp = reinterpret_cast<uint32_t __attribute__((address_space(3)))*>(
      (uint32_t)reinterpret_cast<uintptr_t>(l));
  __builtin_amdgcn_global_load_lds(gp, lp, 16, 0, 0);
}

// ---------------- fp32 -> bf16 conversion ----------------
__global__ __launch_bounds__(256) void cvt_bf16_k(const float* __restrict__ in,
                                                  ushort* __restrict__ out, int n4) {
  int i = blockIdx.x * 256 + threadIdx.x;
  if (i < n4) {
    float4 v = ((const float4*)in)[i];
    ushort4 u;
    u.x = f2bf(v.x); u.y = f2bf(v.y); u.z = f2bf(v.z); u.w = f2bf(v.w);
    ((ushort4*)out)[i] = u;
  }
}

// ---------------- NT GEMM: C[M,N] = A[M,K] * B[N,K]^T (bf16 in, f32 acc) ----
#define EPI_QKV 0
#define EPI_RK 1
#define EPI_F32 2
#define EPI_RELU_BF16 3
#define EPI_BIAS_F32 4

template <int EPI>
__global__ __launch_bounds__(256) void gemm_nt(
    const ushort* __restrict__ A, const ushort* __restrict__ B, int M, int N, int K,
    float* __restrict__ Cf, ushort* __restrict__ Cb, const float* __restrict__ bias,
    ushort* __restrict__ qw, ushort* __restrict__ qr, ushort* __restrict__ kbuf,
    ushort* __restrict__ vt, const float* __restrict__ rwb, const float* __restrict__ rrb) {
  __shared__ ushort As[128 * 32];
  __shared__ ushort Bs[128 * 32];
  const int t = threadIdx.x;
  const int lane = t & 63, wv = t >> 6;
  const int wr = wv >> 1, wc = wv & 1;
  const int m0 = blockIdx.y * 128, n0 = blockIdx.x * 128;
  const int rif = lane & 15;
  const int kb = (lane >> 4) * 16;

  f32x4 acc[4][4] = {};
  const char* Ab = (const char*)A;
  const char* Bb = (const char*)B;
  const int arow = t >> 2;
  const int acol = (t & 3) * 16;

  for (int k0 = 0; k0 < K; k0 += 32) {
    __syncthreads();
    {
      size_t abase = ((size_t)(m0 + arow) * K + k0) * 2 + acol;
      gload_lds16(Ab + abase, (char*)As + t * 16);
      gload_lds16(Ab + abase + (size_t)64 * K * 2, (char*)As + t * 16 + 4096);
      size_t bbase = ((size_t)(n0 + arow) * K + k0) * 2 + acol;
      gload_lds16(Bb + bbase, (char*)Bs + t * 16);
      gload_lds16(Bb + bbase + (size_t)64 * K * 2, (char*)Bs + t * 16 + 4096);
    }
    __syncthreads();
    bf16x8 af[4], bfr[4];
#pragma unroll
    for (int m = 0; m < 4; m++)
      af[m] = *(const bf16x8*)((const char*)As + (wr * 64 + m * 16 + rif) * 64 + kb);
#pragma unroll
    for (int n = 0; n < 4; n++)
      bfr[n] = *(const bf16x8*)((const char*)Bs + (wc * 64 + n * 16 + rif) * 64 + kb);
#pragma unroll
    for (int m = 0; m < 4; m++)
#pragma unroll
      for (int n = 0; n < 4; n++)
        acc[m][n] = __builtin_amdgcn_mfma_f32_16x16x32_bf16(af[m], bfr[n], acc[m][n], 0, 0, 0);
  }

  const int rbase = (lane >> 4) * 4;
#pragma unroll
  for (int m = 0; m < 4; m++) {
#pragma unroll
    for (int n = 0; n < 4; n++) {
#pragma unroll
      for (int reg = 0; reg < 4; reg++) {
        int gr = m0 + wr * 64 + m * 16 + rbase + reg;
        int gc = n0 + wc * 64 + n * 16 + (lane & 15);
        float v = acc[m][n][reg];
        if (EPI == EPI_F32) {
          Cf[(size_t)gr * N + gc] = v;
        } else if (EPI == EPI_BIAS_F32) {
          Cf[(size_t)gr * N + gc] = v + bias[gc];
        } else if (EPI == EPI_RELU_BF16) {
          Cb[(size_t)gr * N + gc] = f2bf(fmaxf(v + bias[gc], 0.f));
        } else if (EPI == EPI_RK) {
          int hn = gc >> 6, hd = gc & 63;
          Cb[((size_t)hn * QL + gr) * 64 + hd] = f2bf(v);
        } else {  // EPI_QKV
          int which = gc >> 10, hh = gc & 1023;
          int hn = hh >> 6, hd = hh & 63;
          int qi = gr >> 1, qb = gr & 1;
          size_t off = ((size_t)(qb * NHEAD + hn) * QL + qi) * 64 + hd;
          if (which == 0) {
            qw[off] = f2bf(v + rwb[hh]);
            qr[off] = f2bf(v + rrb[hh]);
          } else if (which == 1) {
            kbuf[off] = f2bf(v);
          } else {
            vt[((size_t)(qb * NHEAD + hn) * 64 + hd) * QL + qi] = f2bf(v);
          }
        }
      }
    }
  }
}

// ---------------- fused causal attention with TXL rel-shift ----------------
// LDS = K(8K) + V(8K) + R(16K) = 32KB -> 4-5 blocks/CU. BD rel-shift gather is
// in-register (cvt_pk + ds_bpermute within 16-lane row groups). P goes through
// the (dead after QK^T) K_lds region, 16B-aligned swizzled; extra barrier makes
// the cross-wave buffer reuse safe. Softmax in exp2 domain.
__global__ __launch_bounds__(256) void flash_attn(
    const ushort* __restrict__ Qw, const ushort* __restrict__ Qr,
    const ushort* __restrict__ Kb, const ushort* __restrict__ Vt,
    const ushort* __restrict__ Rk, ushort* __restrict__ out) {
  __shared__ ushort K_lds[64 * 64];   // K tile, then reused as per-wave P buffer
  __shared__ ushort V_lds[64 * 64];   // [d][j], swizzled
  __shared__ ushort R_lds[128 * 64];  // rows T0..T0+127, swizzled

  const int t = threadIdx.x;
  const int lane = t & 63, wv = t >> 6;
  const int bn = blockIdx.y;
  const int qb = bn >> 4, hn = bn & 15;
  const int i0 = (gridDim.x - 1 - blockIdx.x) * 64;  // heavy tiles first
  const int iw = i0 + wv * 16;
  const int c4 = lane & 15, g4 = lane >> 4;

  const char* Qwb = (const char*)(Qw + (size_t)bn * QL * 64);
  const char* Qrb = (const char*)(Qr + (size_t)bn * QL * 64);
  const char* Kbb = (const char*)(Kb + (size_t)bn * QL * 64);
  const char* Vtb = (const char*)(Vt + (size_t)bn * 64 * QL);
  const char* Rkb = (const char*)(Rk + (size_t)hn * QL * 64);

  bf16x8 qwf[2], qrf[2];
#pragma unroll
  for (int kk = 0; kk < 2; kk++) {
    qwf[kk] = *(const bf16x8*)(Qwb + (size_t)(iw + c4) * 128 + kk * 64 + g4 * 16);
    qrf[kk] = *(const bf16x8*)(Qrb + (size_t)(iw + c4) * 128 + kk * 64 + g4 * 16);
  }

  // bpermute source-lane addresses for the rel-shift gather (per reg)
  int addrs[4];
#pragma unroll
  for (int reg = 0; reg < 4; reg++) {
    int rr = g4 * 4 + reg;
    addrs[reg] = ((lane & 48) | ((c4 + 15 - rr) & 15)) << 2;
  }

  f32x4 o_acc[4] = {};
  float m_run[4], l_run[4];
#pragma unroll
  for (int r = 0; r < 4; r++) { m_run[r] = -3.0e38f; l_run[r] = 0.f; }

  const float SCALE2 = 0.125f * 1.44269504088896340736f;  // exp2 domain

  for (int j0 = 0; j0 <= i0; j0 += 64) {
    const int T0 = j0 - i0 + (QL - 64);
    __syncthreads();
    // --- stage K, V (8KB each); global source pre-swizzled, linear LDS dest
#pragma unroll
    for (int p = 0; p < 2; p++) {
      int o = t * 16 + p * 4096;
      int row = o >> 7, ch16 = ((((o & 127) >> 4) ^ (row & 7)) << 4);
      gload_lds16(Kbb + (size_t)(j0 + row) * 128 + ch16, (char*)K_lds + o);
      gload_lds16(Vtb + (size_t)row * (QL * 2) + (size_t)j0 * 2 + ch16, (char*)V_lds + o);
    }
    // --- stage R (16KB, rows T0..T0+127 clamped)
#pragma unroll
    for (int p = 0; p < 4; p++) {
      int o = t * 16 + p * 4096;
      int r = o >> 7;
      int srow = T0 + r; srow = srow > QL - 1 ? QL - 1 : srow;  // masked cells only
      int ch16 = ((((o & 127) >> 4) ^ (r & 7)) << 4);
      gload_lds16(Rkb + (size_t)srow * 128 + ch16, (char*)R_lds + o);
    }
    __syncthreads();

    f32x4 acc_s[4] = {};
    f32x4 acc_bd[5] = {};
    const int baseloc = 48 - wv * 16;
    __builtin_amdgcn_s_setprio(1);
#pragma unroll
    for (int kk = 0; kk < 2; kk++) {
      const int sw = (((kk * 4 + g4) ^ (c4 & 7)) << 4);
#pragma unroll
      for (int nf = 0; nf < 4; nf++) {
        bf16x8 bk = *(const bf16x8*)((const char*)K_lds + (nf * 16 + c4) * 128 + sw);
        acc_s[nf] = __builtin_amdgcn_mfma_f32_16x16x32_bf16(qwf[kk], bk, acc_s[nf], 0, 0, 0);
      }
#pragma unroll
      for (int tf = 0; tf < 5; tf++) {
        int oo = baseloc + tf * 16 + c4;  // oo&7 == c4&7
        bf16x8 br = *(const bf16x8*)((const char*)R_lds + oo * 128 + sw);
        acc_bd[tf] = __builtin_amdgcn_mfma_f32_16x16x32_bf16(qrf[kk], br, acc_bd[tf], 0, 0, 0);
      }
    }
    __builtin_amdgcn_s_setprio(0);

    // pack BD' (tf, tf+1) pairs as bf16x2 for the in-register rel-shift gather
    uint32_t pk[4][4];
#pragma unroll
    for (int nf = 0; nf < 4; nf++)
#pragma unroll
      for (int reg = 0; reg < 4; reg++)
        asm("v_cvt_pk_bf16_f32 %0, %1, %2"
            : "=v"(pk[nf][reg])
            : "v"(acc_bd[nf][reg]), "v"(acc_bd[nf + 1][reg]));

    float sv[4][4];
    float rowmax[4] = {-3.0e38f, -3.0e38f, -3.0e38f, -3.0e38f};
#pragma unroll
    for (int nf = 0; nf < 4; nf++) {
#pragma unroll
      for (int reg = 0; reg < 4; reg++) {
        int rr = g4 * 4 + reg;
        int jg = j0 + nf * 16 + c4;
        int ig = iw + rr;
        uint32_t pulled = (uint32_t)__builtin_amdgcn_ds_bpermute(addrs[reg], (int)pk[nf][reg]);
        uint32_t bits = (c4 > rr) ? (pulled & 0xffff0000u) : (pulled << 16);
        float v = (acc_s[nf][reg] + __uint_as_float(bits)) * SCALE2;
        v = (jg <= ig) ? v : -3.0e38f;
        sv[nf][reg] = v;
        rowmax[reg] = fmaxf(rowmax[reg], v);
      }
    }
#pragma unroll
    for (int reg = 0; reg < 4; reg++) {
      float rm = rowmax[reg];
      rm = fmaxf(rm, __shfl_xor(rm, 1));
      rm = fmaxf(rm, __shfl_xor(rm, 2));
      rm = fmaxf(rm, __shfl_xor(rm, 4));
      rm = fmaxf(rm, __shfl_xor(rm, 8));
      float mnew = fmaxf(m_run[reg], rm);
      float alpha = __builtin_amdgcn_exp2f(m_run[reg] - mnew);
      float rsum = 0.f;
#pragma unroll
      for (int nf = 0; nf < 4; nf++) {
        float p = __builtin_amdgcn_exp2f(sv[nf][reg] - mnew);
        sv[nf][reg] = p;
        rsum += p;
      }
      rsum += __shfl_xor(rsum, 1);
      rsum += __shfl_xor(rsum, 2);
      rsum += __shfl_xor(rsum, 4);
      rsum += __shfl_xor(rsum, 8);
      l_run[reg] = l_run[reg] * alpha + rsum;
      m_run[reg] = mnew;
#pragma unroll
      for (int df = 0; df < 4; df++) o_acc[df][reg] *= alpha;
    }

    // K_lds is dead (all waves past QK^T after this barrier) -> P buffer
    __syncthreads();
    {
      char* pb = (char*)K_lds + wv * 2048;
#pragma unroll
      for (int nf = 0; nf < 4; nf++)
#pragma unroll
        for (int reg = 0; reg < 4; reg++) {
          int row = g4 * 4 + reg, col = nf * 16 + c4;
          int byt = row * 128 + ((((col >> 3) ^ (row & 7))) << 4) + (col & 7) * 2;
          *(ushort*)(pb + byt) = f2bf(sv[nf][reg]);
        }
    }
    __builtin_amdgcn_s_setprio(1);
#pragma unroll
    for (int kk = 0; kk < 2; kk++) {
      const char* pb = (const char*)K_lds + wv * 2048;
      bf16x8 pa = *(const bf16x8*)(pb + c4 * 128 + (((kk * 4 + g4) ^ (c4 & 7)) << 4));
      const int sw = (((kk * 4 + g4) ^ (c4 & 7)) << 4);
#pragma unroll
      for (int df = 0; df < 4; df++) {
        bf16x8 bv = *(const bf16x8*)((const char*)V_lds + (df * 16 + c4) * 128 + sw);
        o_acc[df] = __builtin_amdgcn_mfma_f32_16x16x32_bf16(pa, bv, o_acc[df], 0, 0, 0);
      }
    }
    __builtin_amdgcn_s_setprio(0);
  }

#pragma unroll
  for (int reg = 0; reg < 4; reg++) {
    float inv = 1.0f / l_run[reg];
    int ig = iw + g4 * 4 + reg;
    size_t grow = (size_t)(ig * 2 + qb) * 1024 + hn * 64;
#pragma unroll
    for (int df = 0; df < 4; df++)
      out[grow + df * 16 + c4] = f2bf(o_acc[df][reg] * inv);
  }
}

// ---------------- residual + LayerNorm ----------------
template <bool WB>
__global__ __launch_bounds__(256) void ln_res(
    const float* __restrict__ xa, const float* __restrict__ xb,
    const float* __restrict__ g, const float* __restrict__ bt,
    float* __restrict__ of, ushort* __restrict__ ob) {
  __shared__ float red[8];
  const int row = blockIdx.x;
  const int t = threadIdx.x;
  const int lane = t & 63, wv = t >> 6;
  const float4 a = *(const float4*)(xa + (size_t)row * 1024 + t * 4);
  const float4 c = *(const float4*)(xb + (size_t)row * 1024 + t * 4);
  float x[4] = {a.x + c.x, a.y + c.y, a.z + c.z, a.w + c.w};
  float s = x[0] + x[1] + x[2] + x[3];
  for (int m = 1; m < 64; m <<= 1) s += __shfl_xor(s, m);
  if (lane == 0) red[wv] = s;
  __syncthreads();
  float mu = (red[0] + red[1] + red[2] + red[3]) * (1.f / 1024.f);
  float d[4];
  float ss = 0.f;
#pragma unroll
  for (int i = 0; i < 4; i++) { d[i] = x[i] - mu; ss += d[i] * d[i]; }
  for (int m = 1; m < 64; m <<= 1) ss += __shfl_xor(ss, m);
  if (lane == 0) red[4 + wv] = ss;
  __syncthreads();
  float var = (red[4] + red[5] + red[6] + red[7]) * (1.f / 1024.f);
  float rs = rsqrtf(var + 1e-5f);
  float4 gv = *(const float4*)(g + t * 4);
  float4 bv = *(const float4*)(bt + t * 4);
  float y[4] = {d[0] * rs * gv.x + bv.x, d[1] * rs * gv.y + bv.y,
                d[2] * rs * gv.z + bv.z, d[3] * rs * gv.w + bv.w};
  float4 yo = make_float4(y[0], y[1], y[2], y[3]);
  *(float4*)(of + (size_t)row * 1024 + t * 4) = yo;
  if (WB) {
    ushort4 u;
    u.x = f2bf(y[0]); u.y = f2bf(y[1]); u.z = f2bf(y[2]); u.w = f2bf(y[3]);
    *(ushort4*)(ob + (size_t)row * 1024 + t * 4) = u;
  }
}

// ---------------- host orchestration ----------------
extern "C" void kernel_launch(void* const* d_in, const int* in_sizes, int n_in,
                              void* d_out, int out_size, void* d_ws, size_t ws_size,
                              hipStream_t stream) {
  const float* dec_inp = (const float*)d_in[0];
  const float* r_in = (const float*)d_in[1];
  const float* rwb = (const float*)d_in[2];
  const float* rrb = (const float*)d_in[3];
  const float* qkv_w = (const float*)d_in[4];
  const float* rnet_w = (const float*)d_in[5];
  const float* o_w = (const float*)d_in[6];
  const float* ln_attn_g = (const float*)d_in[7];
  const float* ln_attn_b = (const float*)d_in[8];
  const float* w1 = (const float*)d_in[9];
  const float* b1 = (const float*)d_in[10];
  const float* w2 = (const float*)d_in[11];
  const float* b2 = (const float*)d_in[12];
  const float* ln_ff_g = (const float*)d_in[13];
  const float* ln_ff_b = (const float*)d_in[14];
  float* out = (float*)d_out;

  char* ws = (char*)d_ws;
  size_t off = 0;
  auto alloc = [&](size_t bytes) {
    char* p = ws + off;
    off += (bytes + 255) & ~(size_t)255;
    return p;
  };
  const int ROWS = QL * 2;
  ushort* qkvw_b = (ushort*)alloc((size_t)3072 * 1024 * 2);
  ushort* rnetw_b = (ushort*)alloc((size_t)1024 * 1024 * 2);
  ushort* ow_b = (ushort*)alloc((size_t)1024 * 1024 * 2);
  ushort* w1_b = (ushort*)alloc((size_t)4096 * 1024 * 2);
  ushort* w2_b = (ushort*)alloc((size_t)1024 * 4096 * 2);
  ushort* x_b = (ushort*)alloc((size_t)ROWS * 1024 * 2);
  ushort* r_b = (ushort*)alloc((size_t)QL * 1024 * 2);
  ushort* Qw = (ushort*)alloc((size_t)32 * QL * 64 * 2);
  ushort* Qr = (ushort*)alloc((size_t)32 * QL * 64 * 2);
  ushort* Kb = (ushort*)alloc((size_t)32 * QL * 64 * 2);
  ushort* Vt = (ushort*)alloc((size_t)32 * 64 * QL * 2);
  ushort* rk = (ushort*)alloc((size_t)16 * QL * 64 * 2);
  ushort* avec = (ushort*)alloc((size_t)ROWS * 1024 * 2);
  float* attn_out = (float*)alloc((size_t)ROWS * 1024 * 4);
  float* x1f = (float*)alloc((size_t)ROWS * 1024 * 4);
  ushort* x1b = (ushort*)alloc((size_t)ROWS * 1024 * 2);
  ushort* hidden = (ushort*)alloc((size_t)ROWS * 4096 * 2);
  float* core = (float*)alloc((size_t)ROWS * 1024 * 4);

  auto cvt = [&](const float* src, ushort* dst, int n) {
    int n4 = n / 4;
    cvt_bf16_k<<<n4 / 256, 256, 0, stream>>>(src, dst, n4);
  };
  cvt(qkv_w, qkvw_b, 3072 * 1024);
  cvt(rnet_w, rnetw_b, 1024 * 1024);
  cvt(o_w, ow_b, 1024 * 1024);
  cvt(w1, w1_b, 4096 * 1024);
  cvt(w2, w2_b, 1024 * 4096);
  cvt(dec_inp, x_b, ROWS * 1024);
  cvt(r_in, r_b, QL * 1024);

  gemm_nt<EPI_QKV><<<dim3(3072 / 128, ROWS / 128), 256, 0, stream>>>(
      x_b, qkvw_b, ROWS, 3072, 1024, nullptr, nullptr, nullptr, Qw, Qr, Kb, Vt, rwb, rrb);
  gemm_nt<EPI_RK><<<dim3(1024 / 128, QL / 128), 256, 0, stream>>>(
      r_b, rnetw_b, QL, 1024, 1024, nullptr, rk, nullptr, nullptr, nullptr, nullptr, nullptr,
      nullptr, nullptr);
  flash_attn<<<dim3(QL / 64, 32), 256, 0, stream>>>(Qw, Qr, Kb, Vt, rk, avec);
  gemm_nt<EPI_F32><<<dim3(1024 / 128, ROWS / 128), 256, 0, stream>>>(
      avec, ow_b, ROWS, 1024, 1024, attn_out, nullptr, nullptr, nullptr, nullptr, nullptr,
      nullptr, nullptr, nullptr);
  ln_res<true><<<ROWS, 256, 0, stream>>>(dec_inp, attn_out, ln_attn_g, ln_attn_b, x1f, x1b);
  gemm_nt<EPI_RELU_BF16><<<dim3(4096 / 128, ROWS / 128), 256, 0, stream>>>(
      x1b, w1_b, ROWS, 4096, 1024, nullptr, hidden, b1, nullptr, nullptr, nullptr, nullptr,
      nullptr, nullptr);
  gemm_nt<EPI_BIAS_F32><<<dim3(1024 / 128, ROWS / 128), 256, 0, stream>>>(
      hidden, w2_b, ROWS, 1024, 4096, core, nullptr, b2, nullptr, nullptr, nullptr, nullptr,
      nullptr, nullptr);
  ln_res<false><<<ROWS, 256, 0, stream>>>(x1f, core, ln_ff_g, ln_ff_b, out, nullptr);
}

// Round 5
// 400.819 us; speedup vs baseline: 1.3265x; 1.1850x over previous
//
#include <hip/hip_runtime.h>
#include <stdint.h>

#define QL 2048
#define NHEAD 16
#define DHEAD 64
#define DMODEL 1024
#define DINNER 4096

typedef __attribute__((ext_vector_type(8))) short bf16x8;
typedef __attribute__((ext_vector_type(4))) float f32x4;

__device__ __forceinline__ ushort f2bf(float f) {
  uint32_t u = __float_as_uint(f);
  u = (u + 0x7fffu + ((u >> 16) & 1u)) >> 16;
  return (ushort)u;
}
__device__ __forceinline__ float bf2f(ushort u) {
  return __uint_as_float(((uint32_t)u) << 16);
}

__device__ __forceinline__ void gload_lds16(const void* g, void* l) {
  auto gp = reinterpret_cast<const uint32_t __attribute__((address_space(1)))*>(
      reinterpret_cast<uintptr_t>(g));
  auto lp = reinterpret_cast<uint32_t __attribute__((address_space(3)))*>(
      (uint32_t)reinterpret_cast<uintptr_t>(l));
  __builtin_amdgcn_global_load_lds(gp, lp, 16, 0, 0);
}

// ---------------- fp32 -> bf16 conversion ----------------
__global__ __launch_bounds__(256) void cvt_bf16_k(const float* __restrict__ in,
                                                  ushort* __restrict__ out, int n4) {
  int i = blockIdx.x * 256 + threadIdx.x;
  if (i < n4) {
    float4 v = ((const float4*)in)[i];
    ushort4 u;
    u.x = f2bf(v.x); u.y = f2bf(v.y); u.z = f2bf(v.z); u.w = f2bf(v.w);
    ((ushort4*)out)[i] = u;
  }
}

// ---------------- NT GEMM: C[M,N] = A[M,K] * B[N,K]^T (bf16 in, f32 acc) ----
#define EPI_QKV 0
#define EPI_RK 1
#define EPI_F32 2
#define EPI_RELU_BF16 3
#define EPI_BIAS_F32 4

template <int EPI>
__global__ __launch_bounds__(256) void gemm_nt(
    const ushort* __restrict__ A, const ushort* __restrict__ B, int M, int N, int K,
    float* __restrict__ Cf, ushort* __restrict__ Cb, const float* __restrict__ bias,
    ushort* __restrict__ qw, ushort* __restrict__ qr, ushort* __restrict__ kbuf,
    ushort* __restrict__ vt, const float* __restrict__ rwb, const float* __restrict__ rrb) {
  __shared__ ushort As[128 * 32];
  __shared__ ushort Bs[128 * 32];
  const int t = threadIdx.x;
  const int lane = t & 63, wv = t >> 6;
  const int wr = wv >> 1, wc = wv & 1;
  const int m0 = blockIdx.y * 128, n0 = blockIdx.x * 128;
  const int rif = lane & 15;
  const int kb = (lane >> 4) * 16;

  f32x4 acc[4][4] = {};
  const char* Ab = (const char*)A;
  const char* Bb = (const char*)B;
  const int arow = t >> 2;
  const int acol = (t & 3) * 16;

  for (int k0 = 0; k0 < K; k0 += 32) {
    __syncthreads();
    {
      size_t abase = ((size_t)(m0 + arow) * K + k0) * 2 + acol;
      gload_lds16(Ab + abase, (char*)As + t * 16);
      gload_lds16(Ab + abase + (size_t)64 * K * 2, (char*)As + t * 16 + 4096);
      size_t bbase = ((size_t)(n0 + arow) * K + k0) * 2 + acol;
      gload_lds16(Bb + bbase, (char*)Bs + t * 16);
      gload_lds16(Bb + bbase + (size_t)64 * K * 2, (char*)Bs + t * 16 + 4096);
    }
    __syncthreads();
    bf16x8 af[4], bfr[4];
#pragma unroll
    for (int m = 0; m < 4; m++)
      af[m] = *(const bf16x8*)((const char*)As + (wr * 64 + m * 16 + rif) * 64 + kb);
#pragma unroll
    for (int n = 0; n < 4; n++)
      bfr[n] = *(const bf16x8*)((const char*)Bs + (wc * 64 + n * 16 + rif) * 64 + kb);
#pragma unroll
    for (int m = 0; m < 4; m++)
#pragma unroll
      for (int n = 0; n < 4; n++)
        acc[m][n] = __builtin_amdgcn_mfma_f32_16x16x32_bf16(af[m], bfr[n], acc[m][n], 0, 0, 0);
  }

  const int rbase = (lane >> 4) * 4;
#pragma unroll
  for (int m = 0; m < 4; m++) {
#pragma unroll
    for (int n = 0; n < 4; n++) {
#pragma unroll
      for (int reg = 0; reg < 4; reg++) {
        int gr = m0 + wr * 64 + m * 16 + rbase + reg;
        int gc = n0 + wc * 64 + n * 16 + (lane & 15);
        float v = acc[m][n][reg];
        if (EPI == EPI_F32) {
          Cf[(size_t)gr * N + gc] = v;
        } else if (EPI == EPI_BIAS_F32) {
          Cf[(size_t)gr * N + gc] = v + bias[gc];
        } else if (EPI == EPI_RELU_BF16) {
          Cb[(size_t)gr * N + gc] = f2bf(fmaxf(v + bias[gc], 0.f));
        } else if (EPI == EPI_RK) {
          int hn = gc >> 6, hd = gc & 63;
          Cb[((size_t)hn * QL + gr) * 64 + hd] = f2bf(v);
        } else {  // EPI_QKV
          int which = gc >> 10, hh = gc & 1023;
          int hn = hh >> 6, hd = hh & 63;
          int qi = gr >> 1, qb = gr & 1;
          size_t off = ((size_t)(qb * NHEAD + hn) * QL + qi) * 64 + hd;
          if (which == 0) {
            qw[off] = f2bf(v + rwb[hh]);
            qr[off] = f2bf(v + rrb[hh]);
          } else if (which == 1) {
            kbuf[off] = f2bf(v);
          } else {
            vt[((size_t)(qb * NHEAD + hn) * 64 + hd) * QL + qi] = f2bf(v);
          }
        }
      }
    }
  }
}

// ---------------- fused causal attention with TXL rel-shift ----------------
// Load-balanced tile pairing: block k handles i-tiles (31-k) and k -> every
// block = exactly 34 j-iterations. Double-buffered K/V/R (T3 minimum 2-phase):
// stage(next) issued before compute(cur); single raw s_barrier per iteration
// with vmcnt(0) drained AFTER compute (load latency hides under compute).
// Dedicated per-wave P buffer (no second barrier). LDS 72KB -> 2 blocks/CU.
__global__ __launch_bounds__(256) void flash_attn(
    const ushort* __restrict__ Qw, const ushort* __restrict__ Qr,
    const ushort* __restrict__ Kb, const ushort* __restrict__ Vt,
    const ushort* __restrict__ Rk, ushort* __restrict__ out) {
  __shared__ ushort K_lds[2][64 * 64];
  __shared__ ushort V_lds[2][64 * 64];   // [d][j], swizzled
  __shared__ ushort R_lds[2][128 * 64];  // rows T0..T0+127, swizzled
  __shared__ ushort P_lds[4][16 * 64];   // per-wave P, swizzled rows

  const int t = threadIdx.x;
  const int lane = t & 63, wv = t >> 6;
  const int bn = blockIdx.y;
  const int qb = bn >> 4, hn = bn & 15;
  const int c4 = lane & 15, g4 = lane >> 4;

  const char* Qwb = (const char*)(Qw + (size_t)bn * QL * 64);
  const char* Qrb = (const char*)(Qr + (size_t)bn * QL * 64);
  const char* Kbb = (const char*)(Kb + (size_t)bn * QL * 64);
  const char* Vtb = (const char*)(Vt + (size_t)bn * 64 * QL);
  const char* Rkb = (const char*)(Rk + (size_t)hn * QL * 64);

  // bpermute source-lane addresses for the rel-shift gather (per reg)
  int addrs[4];
#pragma unroll
  for (int reg = 0; reg < 4; reg++) {
    int rr = g4 * 4 + reg;
    addrs[reg] = ((lane & 48) | ((c4 + 15 - rr) & 15)) << 2;
  }

  const float SCALE2 = 0.125f * 1.44269504088896340736f;  // exp2 domain

#pragma unroll 1
  for (int ph = 0; ph < 2; ph++) {
    const int itile = (ph == 0) ? (31 - (int)blockIdx.x) : (int)blockIdx.x;
    const int i0 = itile * 64;
    const int iw = i0 + wv * 16;
    const int niter = itile + 1;

    bf16x8 qwf[2], qrf[2];
#pragma unroll
    for (int kk = 0; kk < 2; kk++) {
      qwf[kk] = *(const bf16x8*)(Qwb + (size_t)(iw + c4) * 128 + kk * 64 + g4 * 16);
      qrf[kk] = *(const bf16x8*)(Qrb + (size_t)(iw + c4) * 128 + kk * 64 + g4 * 16);
    }

    f32x4 o_acc[4] = {};
    float m_run[4], l_run[4];
#pragma unroll
    for (int r = 0; r < 4; r++) { m_run[r] = -3.0e38f; l_run[r] = 0.f; }

    // stage one (K,V,R) tile set into buffer b
    auto stage = [&](int b, int j0) {
      const int T0 = j0 - i0 + (QL - 64);
#pragma unroll
      for (int p = 0; p < 2; p++) {
        int o = t * 16 + p * 4096;
        int row = o >> 7, ch16 = ((((o & 127) >> 4) ^ (row & 7)) << 4);
        gload_lds16(Kbb + (size_t)(j0 + row) * 128 + ch16, (char*)K_lds[b] + o);
        gload_lds16(Vtb + (size_t)row * (QL * 2) + (size_t)j0 * 2 + ch16, (char*)V_lds[b] + o);
      }
#pragma unroll
      for (int p = 0; p < 4; p++) {
        int o = t * 16 + p * 4096;
        int r = o >> 7;
        int srow = T0 + r; srow = srow > QL - 1 ? QL - 1 : srow;  // masked cells only
        int ch16 = ((((o & 127) >> 4) ^ (r & 7)) << 4);
        gload_lds16(Rkb + (size_t)srow * 128 + ch16, (char*)R_lds[b] + o);
      }
    };

    // prologue
    stage(0, 0);
    asm volatile("s_waitcnt vmcnt(0)" ::: "memory");
    __builtin_amdgcn_s_barrier();
    __builtin_amdgcn_sched_barrier(0);

    int cur = 0;
#pragma unroll 1
    for (int it = 0; it < niter; ++it) {
      const int j0 = it * 64;
      if (it + 1 < niter) stage(cur ^ 1, j0 + 64);

      f32x4 acc_s[4] = {};
      f32x4 acc_bd[5] = {};
      const int baseloc = 48 - wv * 16;
      __builtin_amdgcn_s_setprio(1);
#pragma unroll
      for (int kk = 0; kk < 2; kk++) {
        const int sw = (((kk * 4 + g4) ^ (c4 & 7)) << 4);
#pragma unroll
        for (int nf = 0; nf < 4; nf++) {
          bf16x8 bk = *(const bf16x8*)((const char*)K_lds[cur] + (nf * 16 + c4) * 128 + sw);
          acc_s[nf] = __builtin_amdgcn_mfma_f32_16x16x32_bf16(qwf[kk], bk, acc_s[nf], 0, 0, 0);
        }
#pragma unroll
        for (int tf = 0; tf < 5; tf++) {
          int oo = baseloc + tf * 16 + c4;  // oo&7 == c4&7
          bf16x8 br = *(const bf16x8*)((const char*)R_lds[cur] + oo * 128 + sw);
          acc_bd[tf] = __builtin_amdgcn_mfma_f32_16x16x32_bf16(qrf[kk], br, acc_bd[tf], 0, 0, 0);
        }
      }
      __builtin_amdgcn_s_setprio(0);

      // pack BD' (tf, tf+1) pairs as bf16x2 for the in-register rel-shift gather
      uint32_t pk[4][4];
#pragma unroll
      for (int nf = 0; nf < 4; nf++)
#pragma unroll
        for (int reg = 0; reg < 4; reg++)
          asm("v_cvt_pk_bf16_f32 %0, %1, %2"
              : "=v"(pk[nf][reg])
              : "v"(acc_bd[nf][reg]), "v"(acc_bd[nf + 1][reg]));

      float sv[4][4];
      float rowmax[4] = {-3.0e38f, -3.0e38f, -3.0e38f, -3.0e38f};
#pragma unroll
      for (int nf = 0; nf < 4; nf++) {
#pragma unroll
        for (int reg = 0; reg < 4; reg++) {
          int rr = g4 * 4 + reg;
          int jg = j0 + nf * 16 + c4;
          int ig = iw + rr;
          uint32_t pulled = (uint32_t)__builtin_amdgcn_ds_bpermute(addrs[reg], (int)pk[nf][reg]);
          uint32_t bits = (c4 > rr) ? (pulled & 0xffff0000u) : (pulled << 16);
          float v = (acc_s[nf][reg] + __uint_as_float(bits)) * SCALE2;
          v = (jg <= ig) ? v : -3.0e38f;
          sv[nf][reg] = v;
          rowmax[reg] = fmaxf(rowmax[reg], v);
        }
      }
#pragma unroll
      for (int reg = 0; reg < 4; reg++) {
        float rm = rowmax[reg];
        rm = fmaxf(rm, __shfl_xor(rm, 1));
        rm = fmaxf(rm, __shfl_xor(rm, 2));
        rm = fmaxf(rm, __shfl_xor(rm, 4));
        rm = fmaxf(rm, __shfl_xor(rm, 8));
        float mnew = fmaxf(m_run[reg], rm);
        float alpha = __builtin_amdgcn_exp2f(m_run[reg] - mnew);
        float rsum = 0.f;
#pragma unroll
        for (int nf = 0; nf < 4; nf++) {
          float p = __builtin_amdgcn_exp2f(sv[nf][reg] - mnew);
          sv[nf][reg] = p;
          rsum += p;
        }
        rsum += __shfl_xor(rsum, 1);
        rsum += __shfl_xor(rsum, 2);
        rsum += __shfl_xor(rsum, 4);
        rsum += __shfl_xor(rsum, 8);
        l_run[reg] = l_run[reg] * alpha + rsum;
        m_run[reg] = mnew;
#pragma unroll
        for (int df = 0; df < 4; df++) o_acc[df][reg] *= alpha;
      }

      // P -> dedicated per-wave buffer (wave-private: no barrier needed)
      {
        char* pb = (char*)P_lds[wv];
#pragma unroll
        for (int nf = 0; nf < 4; nf++)
#pragma unroll
          for (int reg = 0; reg < 4; reg++) {
            int row = g4 * 4 + reg, col = nf * 16 + c4;
            int byt = row * 128 + ((((col >> 3) ^ (row & 7))) << 4) + (col & 7) * 2;
            *(ushort*)(pb + byt) = f2bf(sv[nf][reg]);
          }
      }
      __builtin_amdgcn_s_setprio(1);
#pragma unroll
      for (int kk = 0; kk < 2; kk++) {
        const char* pb = (const char*)P_lds[wv];
        bf16x8 pa = *(const bf16x8*)(pb + c4 * 128 + (((kk * 4 + g4) ^ (c4 & 7)) << 4));
        const int sw = (((kk * 4 + g4) ^ (c4 & 7)) << 4);
#pragma unroll
        for (int df = 0; df < 4; df++) {
          bf16x8 bv = *(const bf16x8*)((const char*)V_lds[cur] + (df * 16 + c4) * 128 + sw);
          o_acc[df] = __builtin_amdgcn_mfma_f32_16x16x32_bf16(pa, bv, o_acc[df], 0, 0, 0);
        }
      }
      __builtin_amdgcn_s_setprio(0);

      // drain this iteration's prefetch (had the whole compute to land), sync
      asm volatile("s_waitcnt vmcnt(0)" ::: "memory");
      __builtin_amdgcn_s_barrier();
      __builtin_amdgcn_sched_barrier(0);
      cur ^= 1;
    }

#pragma unroll
    for (int reg = 0; reg < 4; reg++) {
      float inv = 1.0f / l_run[reg];
      int ig = iw + g4 * 4 + reg;
      size_t grow = (size_t)(ig * 2 + qb) * 1024 + hn * 64;
#pragma unroll
      for (int df = 0; df < 4; df++)
        out[grow + df * 16 + c4] = f2bf(o_acc[df][reg] * inv);
    }
  }
}

// ---------------- residual + LayerNorm ----------------
template <bool WB>
__global__ __launch_bounds__(256) void ln_res(
    const float* __restrict__ xa, const float* __restrict__ xb,
    const float* __restrict__ g, const float* __restrict__ bt,
    float* __restrict__ of, ushort* __restrict__ ob) {
  __shared__ float red[8];
  const int row = blockIdx.x;
  const int t = threadIdx.x;
  const int lane = t & 63, wv = t >> 6;
  const float4 a = *(const float4*)(xa + (size_t)row * 1024 + t * 4);
  const float4 c = *(const float4*)(xb + (size_t)row * 1024 + t * 4);
  float x[4] = {a.x + c.x, a.y + c.y, a.z + c.z, a.w + c.w};
  float s = x[0] + x[1] + x[2] + x[3];
  for (int m = 1; m < 64; m <<= 1) s += __shfl_xor(s, m);
  if (lane == 0) red[wv] = s;
  __syncthreads();
  float mu = (red[0] + red[1] + red[2] + red[3]) * (1.f / 1024.f);
  float d[4];
  float ss = 0.f;
#pragma unroll
  for (int i = 0; i < 4; i++) { d[i] = x[i] - mu; ss += d[i] * d[i]; }
  for (int m = 1; m < 64; m <<= 1) ss += __shfl_xor(ss, m);
  if (lane == 0) red[4 + wv] = ss;
  __syncthreads();
  float var = (red[4] + red[5] + red[6] + red[7]) * (1.f / 1024.f);
  float rs = rsqrtf(var + 1e-5f);
  float4 gv = *(const float4*)(g + t * 4);
  float4 bv = *(const float4*)(bt + t * 4);
  float y[4] = {d[0] * rs * gv.x + bv.x, d[1] * rs * gv.y + bv.y,
                d[2] * rs * gv.z + bv.z, d[3] * rs * gv.w + bv.w};
  float4 yo = make_float4(y[0], y[1], y[2], y[3]);
  *(float4*)(of + (size_t)row * 1024 + t * 4) = yo;
  if (WB) {
    ushort4 u;
    u.x = f2bf(y[0]); u.y = f2bf(y[1]); u.z = f2bf(y[2]); u.w = f2bf(y[3]);
    *(ushort4*)(ob + (size_t)row * 1024 + t * 4) = u;
  }
}

// ---------------- host orchestration ----------------
extern "C" void kernel_launch(void* const* d_in, const int* in_sizes, int n_in,
                              void* d_out, int out_size, void* d_ws, size_t ws_size,
                              hipStream_t stream) {
  const float* dec_inp = (const float*)d_in[0];
  const float* r_in = (const float*)d_in[1];
  const float* rwb = (const float*)d_in[2];
  const float* rrb = (const float*)d_in[3];
  const float* qkv_w = (const float*)d_in[4];
  const float* rnet_w = (const float*)d_in[5];
  const float* o_w = (const float*)d_in[6];
  const float* ln_attn_g = (const float*)d_in[7];
  const float* ln_attn_b = (const float*)d_in[8];
  const float* w1 = (const float*)d_in[9];
  const float* b1 = (const float*)d_in[10];
  const float* w2 = (const float*)d_in[11];
  const float* b2 = (const float*)d_in[12];
  const float* ln_ff_g = (const float*)d_in[13];
  const float* ln_ff_b = (const float*)d_in[14];
  float* out = (float*)d_out;

  char* ws = (char*)d_ws;
  size_t off = 0;
  auto alloc = [&](size_t bytes) {
    char* p = ws + off;
    off += (bytes + 255) & ~(size_t)255;
    return p;
  };
  const int ROWS = QL * 2;
  ushort* qkvw_b = (ushort*)alloc((size_t)3072 * 1024 * 2);
  ushort* rnetw_b = (ushort*)alloc((size_t)1024 * 1024 * 2);
  ushort* ow_b = (ushort*)alloc((size_t)1024 * 1024 * 2);
  ushort* w1_b = (ushort*)alloc((size_t)4096 * 1024 * 2);
  ushort* w2_b = (ushort*)alloc((size_t)1024 * 4096 * 2);
  ushort* x_b = (ushort*)alloc((size_t)ROWS * 1024 * 2);
  ushort* r_b = (ushort*)alloc((size_t)QL * 1024 * 2);
  ushort* Qw = (ushort*)alloc((size_t)32 * QL * 64 * 2);
  ushort* Qr = (ushort*)alloc((size_t)32 * QL * 64 * 2);
  ushort* Kb = (ushort*)alloc((size_t)32 * QL * 64 * 2);
  ushort* Vt = (ushort*)alloc((size_t)32 * 64 * QL * 2);
  ushort* rk = (ushort*)alloc((size_t)16 * QL * 64 * 2);
  ushort* avec = (ushort*)alloc((size_t)ROWS * 1024 * 2);
  float* attn_out = (float*)alloc((size_t)ROWS * 1024 * 4);
  float* x1f = (float*)alloc((size_t)ROWS * 1024 * 4);
  ushort* x1b = (ushort*)alloc((size_t)ROWS * 1024 * 2);
  ushort* hidden = (ushort*)alloc((size_t)ROWS * 4096 * 2);
  float* core = (float*)alloc((size_t)ROWS * 1024 * 4);

  auto cvt = [&](const float* src, ushort* dst, int n) {
    int n4 = n / 4;
    cvt_bf16_k<<<n4 / 256, 256, 0, stream>>>(src, dst, n4);
  };
  cvt(qkv_w, qkvw_b, 3072 * 1024);
  cvt(rnet_w, rnetw_b, 1024 * 1024);
  cvt(o_w, ow_b, 1024 * 1024);
  cvt(w1, w1_b, 4096 * 1024);
  cvt(w2, w2_b, 1024 * 4096);
  cvt(dec_inp, x_b, ROWS * 1024);
  cvt(r_in, r_b, QL * 1024);

  gemm_nt<EPI_QKV><<<dim3(3072 / 128, ROWS / 128), 256, 0, stream>>>(
      x_b, qkvw_b, ROWS, 3072, 1024, nullptr, nullptr, nullptr, Qw, Qr, Kb, Vt, rwb, rrb);
  gemm_nt<EPI_RK><<<dim3(1024 / 128, QL / 128), 256, 0, stream>>>(
      r_b, rnetw_b, QL, 1024, 1024, nullptr, rk, nullptr, nullptr, nullptr, nullptr, nullptr,
      nullptr, nullptr);
  flash_attn<<<dim3(16, 32), 256, 0, stream>>>(Qw, Qr, Kb, Vt, rk, avec);
  gemm_nt<EPI_F32><<<dim3(1024 / 128, ROWS / 128), 256, 0, stream>>>(
      avec, ow_b, ROWS, 1024, 1024, attn_out, nullptr, nullptr, nullptr, nullptr, nullptr,
      nullptr, nullptr, nullptr);
  ln_res<true><<<ROWS, 256, 0, stream>>>(dec_inp, attn_out, ln_attn_g, ln_attn_b, x1f, x1b);
  gemm_nt<EPI_RELU_BF16><<<dim3(4096 / 128, ROWS / 128), 256, 0, stream>>>(
      x1b, w1_b, ROWS, 4096, 1024, nullptr, hidden, b1, nullptr, nullptr, nullptr, nullptr,
      nullptr, nullptr);
  gemm_nt<EPI_BIAS_F32><<<dim3(1024 / 128, ROWS / 128), 256, 0, stream>>>(
      hidden, w2_b, ROWS, 1024, 4096, core, nullptr, b2, nullptr, nullptr, nullptr, nullptr,
      nullptr, nullptr);
  ln_res<false><<<ROWS, 256, 0, stream>>>(x1f, core, ln_ff_g, ln_ff_b, out, nullptr);
}

// Round 6
// 377.946 us; speedup vs baseline: 1.4068x; 1.0605x over previous
//
#include <hip/hip_runtime.h>
#include <stdint.h>

#define QL 2048
#define NHEAD 16
#define DHEAD 64
#define DMODEL 1024
#define DINNER 4096

typedef __attribute__((ext_vector_type(8))) short bf16x8;
typedef __attribute__((ext_vector_type(4))) float f32x4;

__device__ __forceinline__ ushort f2bf(float f) {
  uint32_t u = __float_as_uint(f);
  u = (u + 0x7fffu + ((u >> 16) & 1u)) >> 16;
  return (ushort)u;
}
__device__ __forceinline__ float bf2f(ushort u) {
  return __uint_as_float(((uint32_t)u) << 16);
}

__device__ __forceinline__ void gload_lds16(const void* g, void* l) {
  auto gp = reinterpret_cast<const uint32_t __attribute__((address_space(1)))*>(
      reinterpret_cast<uintptr_t>(g));
  auto lp = reinterpret_cast<uint32_t __attribute__((address_space(3)))*>(
      (uint32_t)reinterpret_cast<uintptr_t>(l));
  __builtin_amdgcn_global_load_lds(gp, lp, 16, 0, 0);
}

// ---------------- fp32 -> bf16 conversion ----------------
__global__ __launch_bounds__(256) void cvt_bf16_k(const float* __restrict__ in,
                                                  ushort* __restrict__ out, int n4) {
  int i = blockIdx.x * 256 + threadIdx.x;
  if (i < n4) {
    float4 v = ((const float4*)in)[i];
    ushort4 u;
    u.x = f2bf(v.x); u.y = f2bf(v.y); u.z = f2bf(v.z); u.w = f2bf(v.w);
    ((ushort4*)out)[i] = u;
  }
}

// ---------------- NT GEMM: C[M,N] = A[M,K] * B[N,K]^T (bf16 in, f32 acc) ----
#define EPI_QKV 0
#define EPI_RK 1
#define EPI_F32 2
#define EPI_RELU_BF16 3
#define EPI_BIAS_F32 4

template <int EPI>
__global__ __launch_bounds__(256) void gemm_nt(
    const ushort* __restrict__ A, const ushort* __restrict__ B, int M, int N, int K,
    float* __restrict__ Cf, ushort* __restrict__ Cb, const float* __restrict__ bias,
    ushort* __restrict__ qw, ushort* __restrict__ qr, ushort* __restrict__ kbuf,
    ushort* __restrict__ vt, const float* __restrict__ rwb, const float* __restrict__ rrb) {
  __shared__ ushort As[128 * 32];
  __shared__ ushort Bs[128 * 32];
  const int t = threadIdx.x;
  const int lane = t & 63, wv = t >> 6;
  const int wr = wv >> 1, wc = wv & 1;
  const int m0 = blockIdx.y * 128, n0 = blockIdx.x * 128;
  const int rif = lane & 15;
  const int kb = (lane >> 4) * 16;

  f32x4 acc[4][4] = {};
  const char* Ab = (const char*)A;
  const char* Bb = (const char*)B;
  const int arow = t >> 2;
  const int acol = (t & 3) * 16;

  for (int k0 = 0; k0 < K; k0 += 32) {
    __syncthreads();
    {
      size_t abase = ((size_t)(m0 + arow) * K + k0) * 2 + acol;
      gload_lds16(Ab + abase, (char*)As + t * 16);
      gload_lds16(Ab + abase + (size_t)64 * K * 2, (char*)As + t * 16 + 4096);
      size_t bbase = ((size_t)(n0 + arow) * K + k0) * 2 + acol;
      gload_lds16(Bb + bbase, (char*)Bs + t * 16);
      gload_lds16(Bb + bbase + (size_t)64 * K * 2, (char*)Bs + t * 16 + 4096);
    }
    __syncthreads();
    bf16x8 af[4], bfr[4];
#pragma unroll
    for (int m = 0; m < 4; m++)
      af[m] = *(const bf16x8*)((const char*)As + (wr * 64 + m * 16 + rif) * 64 + kb);
#pragma unroll
    for (int n = 0; n < 4; n++)
      bfr[n] = *(const bf16x8*)((const char*)Bs + (wc * 64 + n * 16 + rif) * 64 + kb);
#pragma unroll
    for (int m = 0; m < 4; m++)
#pragma unroll
      for (int n = 0; n < 4; n++)
        acc[m][n] = __builtin_amdgcn_mfma_f32_16x16x32_bf16(af[m], bfr[n], acc[m][n], 0, 0, 0);
  }

  const int rbase = (lane >> 4) * 4;
#pragma unroll
  for (int m = 0; m < 4; m++) {
#pragma unroll
    for (int n = 0; n < 4; n++) {
#pragma unroll
      for (int reg = 0; reg < 4; reg++) {
        int gr = m0 + wr * 64 + m * 16 + rbase + reg;
        int gc = n0 + wc * 64 + n * 16 + (lane & 15);
        float v = acc[m][n][reg];
        if (EPI == EPI_F32) {
          Cf[(size_t)gr * N + gc] = v;
        } else if (EPI == EPI_BIAS_F32) {
          Cf[(size_t)gr * N + gc] = v + bias[gc];
        } else if (EPI == EPI_RELU_BF16) {
          Cb[(size_t)gr * N + gc] = f2bf(fmaxf(v + bias[gc], 0.f));
        } else if (EPI == EPI_RK) {
          int hn = gc >> 6, hd = gc & 63;
          Cb[((size_t)hn * QL + gr) * 64 + hd] = f2bf(v);
        } else {  // EPI_QKV
          int which = gc >> 10, hh = gc & 1023;
          int hn = hh >> 6, hd = hh & 63;
          int qi = gr >> 1, qb = gr & 1;
          size_t off = ((size_t)(qb * NHEAD + hn) * QL + qi) * 64 + hd;
          if (which == 0) {
            qw[off] = f2bf(v + rwb[hh]);
            qr[off] = f2bf(v + rrb[hh]);
          } else if (which == 1) {
            kbuf[off] = f2bf(v);
          } else {
            vt[((size_t)(qb * NHEAD + hn) * 64 + hd) * QL + qi] = f2bf(v);
          }
        }
      }
    }
  }
}

// ---- BN=64 variant for N=1024 GEMMs (o-proj, FFN2, rk): 2x the grid size ----
// tile 128x64, 4 waves as 2Mx2N, wave-tile 64x32, acc 4x2, LDS 12KB.
template <int EPI>
__global__ __launch_bounds__(256) void gemm_nt64(
    const ushort* __restrict__ A, const ushort* __restrict__ B, int M, int N, int K,
    float* __restrict__ Cf, ushort* __restrict__ Cb, const float* __restrict__ bias) {
  __shared__ ushort As[128 * 32];
  __shared__ ushort Bs[64 * 32];
  const int t = threadIdx.x;
  const int lane = t & 63, wv = t >> 6;
  const int wr = wv >> 1, wc = wv & 1;
  const int m0 = blockIdx.y * 128, n0 = blockIdx.x * 64;
  const int rif = lane & 15;
  const int kb = (lane >> 4) * 16;

  f32x4 acc[4][2] = {};
  const char* Ab = (const char*)A;
  const char* Bb = (const char*)B;
  const int arow = t >> 2;
  const int acol = (t & 3) * 16;

  for (int k0 = 0; k0 < K; k0 += 32) {
    __syncthreads();
    {
      size_t abase = ((size_t)(m0 + arow) * K + k0) * 2 + acol;
      gload_lds16(Ab + abase, (char*)As + t * 16);
      gload_lds16(Ab + abase + (size_t)64 * K * 2, (char*)As + t * 16 + 4096);
      size_t bbase = ((size_t)(n0 + arow) * K + k0) * 2 + acol;
      gload_lds16(Bb + bbase, (char*)Bs + t * 16);
    }
    __syncthreads();
    bf16x8 af[4], bfr[2];
#pragma unroll
    for (int m = 0; m < 4; m++)
      af[m] = *(const bf16x8*)((const char*)As + (wr * 64 + m * 16 + rif) * 64 + kb);
#pragma unroll
    for (int n = 0; n < 2; n++)
      bfr[n] = *(const bf16x8*)((const char*)Bs + (wc * 32 + n * 16 + rif) * 64 + kb);
#pragma unroll
    for (int m = 0; m < 4; m++)
#pragma unroll
      for (int n = 0; n < 2; n++)
        acc[m][n] = __builtin_amdgcn_mfma_f32_16x16x32_bf16(af[m], bfr[n], acc[m][n], 0, 0, 0);
  }

  const int rbase = (lane >> 4) * 4;
#pragma unroll
  for (int m = 0; m < 4; m++) {
#pragma unroll
    for (int n = 0; n < 2; n++) {
#pragma unroll
      for (int reg = 0; reg < 4; reg++) {
        int gr = m0 + wr * 64 + m * 16 + rbase + reg;
        int gc = n0 + wc * 32 + n * 16 + (lane & 15);
        float v = acc[m][n][reg];
        if (EPI == EPI_F32) {
          Cf[(size_t)gr * N + gc] = v;
        } else if (EPI == EPI_BIAS_F32) {
          Cf[(size_t)gr * N + gc] = v + bias[gc];
        } else {  // EPI_RK
          int hn = gc >> 6, hd = gc & 63;
          Cb[((size_t)hn * QL + gr) * 64 + hd] = f2bf(v);
        }
      }
    }
  }
}

// ---------------- fused causal attention with TXL rel-shift ----------------
// Load-balanced tile pairing: block k handles i-tiles (31-k) and k -> every
// block = exactly 34 j-iterations. Double-buffered K/V/R (T3 minimum 2-phase):
// stage(next) issued before compute(cur); single raw s_barrier per iteration
// with vmcnt(0) drained AFTER compute (load latency hides under compute).
// Dedicated per-wave P buffer (no second barrier). LDS 72KB -> 2 blocks/CU.
__global__ __launch_bounds__(256) void flash_attn(
    const ushort* __restrict__ Qw, const ushort* __restrict__ Qr,
    const ushort* __restrict__ Kb, const ushort* __restrict__ Vt,
    const ushort* __restrict__ Rk, ushort* __restrict__ out) {
  __shared__ ushort K_lds[2][64 * 64];
  __shared__ ushort V_lds[2][64 * 64];   // [d][j], swizzled
  __shared__ ushort R_lds[2][128 * 64];  // rows T0..T0+127, swizzled
  __shared__ ushort P_lds[4][16 * 64];   // per-wave P, swizzled rows

  const int t = threadIdx.x;
  const int lane = t & 63, wv = t >> 6;
  const int bn = blockIdx.y;
  const int qb = bn >> 4, hn = bn & 15;
  const int c4 = lane & 15, g4 = lane >> 4;

  const char* Qwb = (const char*)(Qw + (size_t)bn * QL * 64);
  const char* Qrb = (const char*)(Qr + (size_t)bn * QL * 64);
  const char* Kbb = (const char*)(Kb + (size_t)bn * QL * 64);
  const char* Vtb = (const char*)(Vt + (size_t)bn * 64 * QL);
  const char* Rkb = (const char*)(Rk + (size_t)hn * QL * 64);

  // bpermute source-lane addresses for the rel-shift gather (per reg)
  int addrs[4];
#pragma unroll
  for (int reg = 0; reg < 4; reg++) {
    int rr = g4 * 4 + reg;
    addrs[reg] = ((lane & 48) | ((c4 + 15 - rr) & 15)) << 2;
  }

  const float SCALE2 = 0.125f * 1.44269504088896340736f;  // exp2 domain

#pragma unroll 1
  for (int ph = 0; ph < 2; ph++) {
    const int itile = (ph == 0) ? (31 - (int)blockIdx.x) : (int)blockIdx.x;
    const int i0 = itile * 64;
    const int iw = i0 + wv * 16;
    const int niter = itile + 1;

    bf16x8 qwf[2], qrf[2];
#pragma unroll
    for (int kk = 0; kk < 2; kk++) {
      qwf[kk] = *(const bf16x8*)(Qwb + (size_t)(iw + c4) * 128 + kk * 64 + g4 * 16);
      qrf[kk] = *(const bf16x8*)(Qrb + (size_t)(iw + c4) * 128 + kk * 64 + g4 * 16);
    }

    f32x4 o_acc[4] = {};
    float m_run[4], l_run[4];
#pragma unroll
    for (int r = 0; r < 4; r++) { m_run[r] = -3.0e38f; l_run[r] = 0.f; }

    // stage one (K,V,R) tile set into buffer b
    auto stage = [&](int b, int j0) {
      const int T0 = j0 - i0 + (QL - 64);
#pragma unroll
      for (int p = 0; p < 2; p++) {
        int o = t * 16 + p * 4096;
        int row = o >> 7, ch16 = ((((o & 127) >> 4) ^ (row & 7)) << 4);
        gload_lds16(Kbb + (size_t)(j0 + row) * 128 + ch16, (char*)K_lds[b] + o);
        gload_lds16(Vtb + (size_t)row * (QL * 2) + (size_t)j0 * 2 + ch16, (char*)V_lds[b] + o);
      }
#pragma unroll
      for (int p = 0; p < 4; p++) {
        int o = t * 16 + p * 4096;
        int r = o >> 7;
        int srow = T0 + r; srow = srow > QL - 1 ? QL - 1 : srow;  // masked cells only
        int ch16 = ((((o & 127) >> 4) ^ (r & 7)) << 4);
        gload_lds16(Rkb + (size_t)srow * 128 + ch16, (char*)R_lds[b] + o);
      }
    };

    // prologue
    stage(0, 0);
    asm volatile("s_waitcnt vmcnt(0)" ::: "memory");
    __builtin_amdgcn_s_barrier();
    __builtin_amdgcn_sched_barrier(0);

    int cur = 0;
#pragma unroll 1
    for (int it = 0; it < niter; ++it) {
      const int j0 = it * 64;
      if (it + 1 < niter) stage(cur ^ 1, j0 + 64);

      f32x4 acc_s[4] = {};
      f32x4 acc_bd[5] = {};
      const int baseloc = 48 - wv * 16;
      __builtin_amdgcn_s_setprio(1);
#pragma unroll
      for (int kk = 0; kk < 2; kk++) {
        const int sw = (((kk * 4 + g4) ^ (c4 & 7)) << 4);
#pragma unroll
        for (int nf = 0; nf < 4; nf++) {
          bf16x8 bk = *(const bf16x8*)((const char*)K_lds[cur] + (nf * 16 + c4) * 128 + sw);
          acc_s[nf] = __builtin_amdgcn_mfma_f32_16x16x32_bf16(qwf[kk], bk, acc_s[nf], 0, 0, 0);
        }
#pragma unroll
        for (int tf = 0; tf < 5; tf++) {
          int oo = baseloc + tf * 16 + c4;  // oo&7 == c4&7
          bf16x8 br = *(const bf16x8*)((const char*)R_lds[cur] + oo * 128 + sw);
          acc_bd[tf] = __builtin_amdgcn_mfma_f32_16x16x32_bf16(qrf[kk], br, acc_bd[tf], 0, 0, 0);
        }
      }
      __builtin_amdgcn_s_setprio(0);

      // pack BD' (tf, tf+1) pairs as bf16x2 for the in-register rel-shift gather
      uint32_t pk[4][4];
#pragma unroll
      for (int nf = 0; nf < 4; nf++)
#pragma unroll
        for (int reg = 0; reg < 4; reg++)
          asm("v_cvt_pk_bf16_f32 %0, %1, %2"
              : "=v"(pk[nf][reg])
              : "v"(acc_bd[nf][reg]), "v"(acc_bd[nf + 1][reg]));

      float sv[4][4];
      float rowmax[4] = {-3.0e38f, -3.0e38f, -3.0e38f, -3.0e38f};
#pragma unroll
      for (int nf = 0; nf < 4; nf++) {
#pragma unroll
        for (int reg = 0; reg < 4; reg++) {
          int rr = g4 * 4 + reg;
          int jg = j0 + nf * 16 + c4;
          int ig = iw + rr;
          uint32_t pulled = (uint32_t)__builtin_amdgcn_ds_bpermute(addrs[reg], (int)pk[nf][reg]);
          uint32_t bits = (c4 > rr) ? (pulled & 0xffff0000u) : (pulled << 16);
          float v = (acc_s[nf][reg] + __uint_as_float(bits)) * SCALE2;
          v = (jg <= ig) ? v : -3.0e38f;
          sv[nf][reg] = v;
          rowmax[reg] = fmaxf(rowmax[reg], v);
        }
      }
#pragma unroll
      for (int reg = 0; reg < 4; reg++) {
        float rm = rowmax[reg];
        rm = fmaxf(rm, __shfl_xor(rm, 1));
        rm = fmaxf(rm, __shfl_xor(rm, 2));
        rm = fmaxf(rm, __shfl_xor(rm, 4));
        rm = fmaxf(rm, __shfl_xor(rm, 8));
        float mnew = fmaxf(m_run[reg], rm);
        float alpha = __builtin_amdgcn_exp2f(m_run[reg] - mnew);
        float rsum = 0.f;
#pragma unroll
        for (int nf = 0; nf < 4; nf++) {
          float p = __builtin_amdgcn_exp2f(sv[nf][reg] - mnew);
          sv[nf][reg] = p;
          rsum += p;
        }
        rsum += __shfl_xor(rsum, 1);
        rsum += __shfl_xor(rsum, 2);
        rsum += __shfl_xor(rsum, 4);
        rsum += __shfl_xor(rsum, 8);
        l_run[reg] = l_run[reg] * alpha + rsum;
        m_run[reg] = mnew;
#pragma unroll
        for (int df = 0; df < 4; df++) o_acc[df][reg] *= alpha;
      }

      // P -> dedicated per-wave buffer (wave-private: no barrier needed)
      {
        char* pb = (char*)P_lds[wv];
#pragma unroll
        for (int nf = 0; nf < 4; nf++)
#pragma unroll
          for (int reg = 0; reg < 4; reg++) {
            int row = g4 * 4 + reg, col = nf * 16 + c4;
            int byt = row * 128 + ((((col >> 3) ^ (row & 7))) << 4) + (col & 7) * 2;
            *(ushort*)(pb + byt) = f2bf(sv[nf][reg]);
          }
      }
      __builtin_amdgcn_s_setprio(1);
#pragma unroll
      for (int kk = 0; kk < 2; kk++) {
        const char* pb = (const char*)P_lds[wv];
        bf16x8 pa = *(const bf16x8*)(pb + c4 * 128 + (((kk * 4 + g4) ^ (c4 & 7)) << 4));
        const int sw = (((kk * 4 + g4) ^ (c4 & 7)) << 4);
#pragma unroll
        for (int df = 0; df < 4; df++) {
          bf16x8 bv = *(const bf16x8*)((const char*)V_lds[cur] + (df * 16 + c4) * 128 + sw);
          o_acc[df] = __builtin_amdgcn_mfma_f32_16x16x32_bf16(pa, bv, o_acc[df], 0, 0, 0);
        }
      }
      __builtin_amdgcn_s_setprio(0);

      // drain this iteration's prefetch (had the whole compute to land), sync
      asm volatile("s_waitcnt vmcnt(0)" ::: "memory");
      __builtin_amdgcn_s_barrier();
      __builtin_amdgcn_sched_barrier(0);
      cur ^= 1;
    }

#pragma unroll
    for (int reg = 0; reg < 4; reg++) {
      float inv = 1.0f / l_run[reg];
      int ig = iw + g4 * 4 + reg;
      size_t grow = (size_t)(ig * 2 + qb) * 1024 + hn * 64;
#pragma unroll
      for (int df = 0; df < 4; df++)
        out[grow + df * 16 + c4] = f2bf(o_acc[df][reg] * inv);
    }
  }
}

// ---------------- residual + LayerNorm ----------------
template <bool WB>
__global__ __launch_bounds__(256) void ln_res(
    const float* __restrict__ xa, const float* __restrict__ xb,
    const float* __restrict__ g, const float* __restrict__ bt,
    float* __restrict__ of, ushort* __restrict__ ob) {
  __shared__ float red[8];
  const int row = blockIdx.x;
  const int t = threadIdx.x;
  const int lane = t & 63, wv = t >> 6;
  const float4 a = *(const float4*)(xa + (size_t)row * 1024 + t * 4);
  const float4 c = *(const float4*)(xb + (size_t)row * 1024 + t * 4);
  float x[4] = {a.x + c.x, a.y + c.y, a.z + c.z, a.w + c.w};
  float s = x[0] + x[1] + x[2] + x[3];
  for (int m = 1; m < 64; m <<= 1) s += __shfl_xor(s, m);
  if (lane == 0) red[wv] = s;
  __syncthreads();
  float mu = (red[0] + red[1] + red[2] + red[3]) * (1.f / 1024.f);
  float d[4];
  float ss = 0.f;
#pragma unroll
  for (int i = 0; i < 4; i++) { d[i] = x[i] - mu; ss += d[i] * d[i]; }
  for (int m = 1; m < 64; m <<= 1) ss += __shfl_xor(ss, m);
  if (lane == 0) red[4 + wv] = ss;
  __syncthreads();
  float var = (red[4] + red[5] + red[6] + red[7]) * (1.f / 1024.f);
  float rs = rsqrtf(var + 1e-5f);
  float4 gv = *(const float4*)(g + t * 4);
  float4 bv = *(const float4*)(bt + t * 4);
  float y[4] = {d[0] * rs * gv.x + bv.x, d[1] * rs * gv.y + bv.y,
                d[2] * rs * gv.z + bv.z, d[3] * rs * gv.w + bv.w};
  float4 yo = make_float4(y[0], y[1], y[2], y[3]);
  *(float4*)(of + (size_t)row * 1024 + t * 4) = yo;
  if (WB) {
    ushort4 u;
    u.x = f2bf(y[0]); u.y = f2bf(y[1]); u.z = f2bf(y[2]); u.w = f2bf(y[3]);
    *(ushort4*)(ob + (size_t)row * 1024 + t * 4) = u;
  }
}

// ---------------- host orchestration ----------------
extern "C" void kernel_launch(void* const* d_in, const int* in_sizes, int n_in,
                              void* d_out, int out_size, void* d_ws, size_t ws_size,
                              hipStream_t stream) {
  const float* dec_inp = (const float*)d_in[0];
  const float* r_in = (const float*)d_in[1];
  const float* rwb = (const float*)d_in[2];
  const float* rrb = (const float*)d_in[3];
  const float* qkv_w = (const float*)d_in[4];
  const float* rnet_w = (const float*)d_in[5];
  const float* o_w = (const float*)d_in[6];
  const float* ln_attn_g = (const float*)d_in[7];
  const float* ln_attn_b = (const float*)d_in[8];
  const float* w1 = (const float*)d_in[9];
  const float* b1 = (const float*)d_in[10];
  const float* w2 = (const float*)d_in[11];
  const float* b2 = (const float*)d_in[12];
  const float* ln_ff_g = (const float*)d_in[13];
  const float* ln_ff_b = (const float*)d_in[14];
  float* out = (float*)d_out;

  char* ws = (char*)d_ws;
  size_t off = 0;
  auto alloc = [&](size_t bytes) {
    char* p = ws + off;
    off += (bytes + 255) & ~(size_t)255;
    return p;
  };
  const int ROWS = QL * 2;
  ushort* qkvw_b = (ushort*)alloc((size_t)3072 * 1024 * 2);
  ushort* rnetw_b = (ushort*)alloc((size_t)1024 * 1024 * 2);
  ushort* ow_b = (ushort*)alloc((size_t)1024 * 1024 * 2);
  ushort* w1_b = (ushort*)alloc((size_t)4096 * 1024 * 2);
  ushort* w2_b = (ushort*)alloc((size_t)1024 * 4096 * 2);
  ushort* x_b = (ushort*)alloc((size_t)ROWS * 1024 * 2);
  ushort* r_b = (ushort*)alloc((size_t)QL * 1024 * 2);
  ushort* Qw = (ushort*)alloc((size_t)32 * QL * 64 * 2);
  ushort* Qr = (ushort*)alloc((size_t)32 * QL * 64 * 2);
  ushort* Kb = (ushort*)alloc((size_t)32 * QL * 64 * 2);
  ushort* Vt = (ushort*)alloc((size_t)32 * 64 * QL * 2);
  ushort* rk = (ushort*)alloc((size_t)16 * QL * 64 * 2);
  ushort* avec = (ushort*)alloc((size_t)ROWS * 1024 * 2);
  float* attn_out = (float*)alloc((size_t)ROWS * 1024 * 4);
  float* x1f = (float*)alloc((size_t)ROWS * 1024 * 4);
  ushort* x1b = (ushort*)alloc((size_t)ROWS * 1024 * 2);
  ushort* hidden = (ushort*)alloc((size_t)ROWS * 4096 * 2);
  float* core = (float*)alloc((size_t)ROWS * 1024 * 4);

  auto cvt = [&](const float* src, ushort* dst, int n) {
    int n4 = n / 4;
    cvt_bf16_k<<<n4 / 256, 256, 0, stream>>>(src, dst, n4);
  };
  cvt(qkv_w, qkvw_b, 3072 * 1024);
  cvt(rnet_w, rnetw_b, 1024 * 1024);
  cvt(o_w, ow_b, 1024 * 1024);
  cvt(w1, w1_b, 4096 * 1024);
  cvt(w2, w2_b, 1024 * 4096);
  cvt(dec_inp, x_b, ROWS * 1024);
  cvt(r_in, r_b, QL * 1024);

  gemm_nt<EPI_QKV><<<dim3(3072 / 128, ROWS / 128), 256, 0, stream>>>(
      x_b, qkvw_b, ROWS, 3072, 1024, nullptr, nullptr, nullptr, Qw, Qr, Kb, Vt, rwb, rrb);
  gemm_nt64<EPI_RK><<<dim3(1024 / 64, QL / 128), 256, 0, stream>>>(
      r_b, rnetw_b, QL, 1024, 1024, nullptr, rk, nullptr);
  flash_attn<<<dim3(16, 32), 256, 0, stream>>>(Qw, Qr, Kb, Vt, rk, avec);
  gemm_nt64<EPI_F32><<<dim3(1024 / 64, ROWS / 128), 256, 0, stream>>>(
      avec, ow_b, ROWS, 1024, 1024, attn_out, nullptr, nullptr);
  ln_res<true><<<ROWS, 256, 0, stream>>>(dec_inp, attn_out, ln_attn_g, ln_attn_b, x1f, x1b);
  gemm_nt<EPI_RELU_BF16><<<dim3(4096 / 128, ROWS / 128), 256, 0, stream>>>(
      x1b, w1_b, ROWS, 4096, 1024, nullptr, hidden, b1, nullptr, nullptr, nullptr, nullptr,
      nullptr, nullptr);
  gemm_nt64<EPI_BIAS_F32><<<dim3(1024 / 64, ROWS / 128), 256, 0, stream>>>(
      hidden, w2_b, ROWS, 1024, 4096, core, nullptr, b2);
  ln_res<false><<<ROWS, 256, 0, stream>>>(x1f, core, ln_ff_g, ln_ff_b, out, nullptr);
}

// Round 7
// 358.361 us; speedup vs baseline: 1.4837x; 1.0546x over previous
//
#include <hip/hip_runtime.h>
#include <stdint.h>

#define QL 2048
#define NHEAD 16
#define DHEAD 64
#define DMODEL 1024
#define DINNER 4096

typedef __attribute__((ext_vector_type(8))) short bf16x8;
typedef __attribute__((ext_vector_type(4))) float f32x4;

__device__ __forceinline__ ushort f2bf(float f) {
  uint32_t u = __float_as_uint(f);
  u = (u + 0x7fffu + ((u >> 16) & 1u)) >> 16;
  return (ushort)u;
}
__device__ __forceinline__ float bf2f(ushort u) {
  return __uint_as_float(((uint32_t)u) << 16);
}

__device__ __forceinline__ void gload_lds16(const void* g, void* l) {
  auto gp = reinterpret_cast<const uint32_t __attribute__((address_space(1)))*>(
      reinterpret_cast<uintptr_t>(g));
  auto lp = reinterpret_cast<uint32_t __attribute__((address_space(3)))*>(
      (uint32_t)reinterpret_cast<uintptr_t>(l));
  __builtin_amdgcn_global_load_lds(gp, lp, 16, 0, 0);
}

// ---------------- fp32 -> bf16 conversion ----------------
__global__ __launch_bounds__(256) void cvt_bf16_k(const float* __restrict__ in,
                                                  ushort* __restrict__ out, int n4) {
  int i = blockIdx.x * 256 + threadIdx.x;
  if (i < n4) {
    float4 v = ((const float4*)in)[i];
    ushort4 u;
    u.x = f2bf(v.x); u.y = f2bf(v.y); u.z = f2bf(v.z); u.w = f2bf(v.w);
    ((ushort4*)out)[i] = u;
  }
}

// ---------------- NT GEMM: C[M,N] = A[M,K] * B[N,K]^T (bf16 in, f32 acc) ----
// 2-phase double-buffered (proven schedule from flash R5): stage(next K-tile)
// issued BEFORE compute(cur); one vmcnt(0)+s_barrier after compute per iter.
#define EPI_QKV 0
#define EPI_RK 1
#define EPI_F32 2
#define EPI_RELU_BF16 3
#define EPI_BIAS_F32 4

template <int EPI>
__global__ __launch_bounds__(256) void gemm_nt(
    const ushort* __restrict__ A, const ushort* __restrict__ B, int M, int N, int K,
    float* __restrict__ Cf, ushort* __restrict__ Cb, const float* __restrict__ bias,
    ushort* __restrict__ qw, ushort* __restrict__ qr, ushort* __restrict__ kbuf,
    ushort* __restrict__ vt, const float* __restrict__ rwb, const float* __restrict__ rrb) {
  __shared__ ushort As[2][128 * 32];
  __shared__ ushort Bs[2][128 * 32];
  const int t = threadIdx.x;
  const int lane = t & 63, wv = t >> 6;
  const int wr = wv >> 1, wc = wv & 1;
  const int m0 = blockIdx.y * 128, n0 = blockIdx.x * 128;
  const int rif = lane & 15;
  const int kb = (lane >> 4) * 16;

  f32x4 acc[4][4] = {};
  const char* Ab = (const char*)A;
  const char* Bb = (const char*)B;
  const int arow = t >> 2;
  const int acol = (t & 3) * 16;

  auto stage = [&](int b, int k0) {
    size_t abase = ((size_t)(m0 + arow) * K + k0) * 2 + acol;
    gload_lds16(Ab + abase, (char*)As[b] + t * 16);
    gload_lds16(Ab + abase + (size_t)64 * K * 2, (char*)As[b] + t * 16 + 4096);
    size_t bbase = ((size_t)(n0 + arow) * K + k0) * 2 + acol;
    gload_lds16(Bb + bbase, (char*)Bs[b] + t * 16);
    gload_lds16(Bb + bbase + (size_t)64 * K * 2, (char*)Bs[b] + t * 16 + 4096);
  };

  stage(0, 0);
  asm volatile("s_waitcnt vmcnt(0)" ::: "memory");
  __builtin_amdgcn_s_barrier();
  __builtin_amdgcn_sched_barrier(0);

  int cur = 0;
#pragma unroll 1
  for (int k0 = 0; k0 < K; k0 += 32) {
    if (k0 + 32 < K) stage(cur ^ 1, k0 + 32);
    bf16x8 af[4], bfr[4];
#pragma unroll
    for (int m = 0; m < 4; m++)
      af[m] = *(const bf16x8*)((const char*)As[cur] + (wr * 64 + m * 16 + rif) * 64 + kb);
#pragma unroll
    for (int n = 0; n < 4; n++)
      bfr[n] = *(const bf16x8*)((const char*)Bs[cur] + (wc * 64 + n * 16 + rif) * 64 + kb);
    __builtin_amdgcn_s_setprio(1);
#pragma unroll
    for (int m = 0; m < 4; m++)
#pragma unroll
      for (int n = 0; n < 4; n++)
        acc[m][n] = __builtin_amdgcn_mfma_f32_16x16x32_bf16(af[m], bfr[n], acc[m][n], 0, 0, 0);
    __builtin_amdgcn_s_setprio(0);
    asm volatile("s_waitcnt vmcnt(0)" ::: "memory");
    __builtin_amdgcn_s_barrier();
    __builtin_amdgcn_sched_barrier(0);
    cur ^= 1;
  }

  const int rbase = (lane >> 4) * 4;
#pragma unroll
  for (int m = 0; m < 4; m++) {
#pragma unroll
    for (int n = 0; n < 4; n++) {
#pragma unroll
      for (int reg = 0; reg < 4; reg++) {
        int gr = m0 + wr * 64 + m * 16 + rbase + reg;
        int gc = n0 + wc * 64 + n * 16 + (lane & 15);
        float v = acc[m][n][reg];
        if (EPI == EPI_F32) {
          Cf[(size_t)gr * N + gc] = v;
        } else if (EPI == EPI_BIAS_F32) {
          Cf[(size_t)gr * N + gc] = v + bias[gc];
        } else if (EPI == EPI_RELU_BF16) {
          Cb[(size_t)gr * N + gc] = f2bf(fmaxf(v + bias[gc], 0.f));
        } else if (EPI == EPI_RK) {
          int hn = gc >> 6, hd = gc & 63;
          Cb[((size_t)hn * QL + gr) * 64 + hd] = f2bf(v);
        } else {  // EPI_QKV
          int which = gc >> 10, hh = gc & 1023;
          int hn = hh >> 6, hd = hh & 63;
          int qi = gr >> 1, qb = gr & 1;
          size_t off = ((size_t)(qb * NHEAD + hn) * QL + qi) * 64 + hd;
          if (which == 0) {
            qw[off] = f2bf(v + rwb[hh]);
            qr[off] = f2bf(v + rrb[hh]);
          } else if (which == 1) {
            kbuf[off] = f2bf(v);
          } else {
            vt[((size_t)(qb * NHEAD + hn) * 64 + hd) * QL + qi] = f2bf(v);
          }
        }
      }
    }
  }
}

// ---- BN=64 variant for N=1024 GEMMs (o-proj, FFN2, rk), same 2-phase ----
template <int EPI>
__global__ __launch_bounds__(256) void gemm_nt64(
    const ushort* __restrict__ A, const ushort* __restrict__ B, int M, int N, int K,
    float* __restrict__ Cf, ushort* __restrict__ Cb, const float* __restrict__ bias) {
  __shared__ ushort As[2][128 * 32];
  __shared__ ushort Bs[2][64 * 32];
  const int t = threadIdx.x;
  const int lane = t & 63, wv = t >> 6;
  const int wr = wv >> 1, wc = wv & 1;
  const int m0 = blockIdx.y * 128, n0 = blockIdx.x * 64;
  const int rif = lane & 15;
  const int kb = (lane >> 4) * 16;

  f32x4 acc[4][2] = {};
  const char* Ab = (const char*)A;
  const char* Bb = (const char*)B;
  const int arow = t >> 2;
  const int acol = (t & 3) * 16;

  auto stage = [&](int b, int k0) {
    size_t abase = ((size_t)(m0 + arow) * K + k0) * 2 + acol;
    gload_lds16(Ab + abase, (char*)As[b] + t * 16);
    gload_lds16(Ab + abase + (size_t)64 * K * 2, (char*)As[b] + t * 16 + 4096);
    size_t bbase = ((size_t)(n0 + arow) * K + k0) * 2 + acol;
    gload_lds16(Bb + bbase, (char*)Bs[b] + t * 16);
  };

  stage(0, 0);
  asm volatile("s_waitcnt vmcnt(0)" ::: "memory");
  __builtin_amdgcn_s_barrier();
  __builtin_amdgcn_sched_barrier(0);

  int cur = 0;
#pragma unroll 1
  for (int k0 = 0; k0 < K; k0 += 32) {
    if (k0 + 32 < K) stage(cur ^ 1, k0 + 32);
    bf16x8 af[4], bfr[2];
#pragma unroll
    for (int m = 0; m < 4; m++)
      af[m] = *(const bf16x8*)((const char*)As[cur] + (wr * 64 + m * 16 + rif) * 64 + kb);
#pragma unroll
    for (int n = 0; n < 2; n++)
      bfr[n] = *(const bf16x8*)((const char*)Bs[cur] + (wc * 32 + n * 16 + rif) * 64 + kb);
    __builtin_amdgcn_s_setprio(1);
#pragma unroll
    for (int m = 0; m < 4; m++)
#pragma unroll
      for (int n = 0; n < 2; n++)
        acc[m][n] = __builtin_amdgcn_mfma_f32_16x16x32_bf16(af[m], bfr[n], acc[m][n], 0, 0, 0);
    __builtin_amdgcn_s_setprio(0);
    asm volatile("s_waitcnt vmcnt(0)" ::: "memory");
    __builtin_amdgcn_s_barrier();
    __builtin_amdgcn_sched_barrier(0);
    cur ^= 1;
  }

  const int rbase = (lane >> 4) * 4;
#pragma unroll
  for (int m = 0; m < 4; m++) {
#pragma unroll
    for (int n = 0; n < 2; n++) {
#pragma unroll
      for (int reg = 0; reg < 4; reg++) {
        int gr = m0 + wr * 64 + m * 16 + rbase + reg;
        int gc = n0 + wc * 32 + n * 16 + (lane & 15);
        float v = acc[m][n][reg];
        if (EPI == EPI_F32) {
          Cf[(size_t)gr * N + gc] = v;
        } else if (EPI == EPI_BIAS_F32) {
          Cf[(size_t)gr * N + gc] = v + bias[gc];
        } else {  // EPI_RK
          int hn = gc >> 6, hd = gc & 63;
          Cb[((size_t)hn * QL + gr) * 64 + hd] = f2bf(v);
        }
      }
    }
  }
}

// ---------------- fused causal attention with TXL rel-shift ----------------
// (unchanged from R6)
__global__ __launch_bounds__(256) void flash_attn(
    const ushort* __restrict__ Qw, const ushort* __restrict__ Qr,
    const ushort* __restrict__ Kb, const ushort* __restrict__ Vt,
    const ushort* __restrict__ Rk, ushort* __restrict__ out) {
  __shared__ ushort K_lds[2][64 * 64];
  __shared__ ushort V_lds[2][64 * 64];   // [d][j], swizzled
  __shared__ ushort R_lds[2][128 * 64];  // rows T0..T0+127, swizzled
  __shared__ ushort P_lds[4][16 * 64];   // per-wave P, swizzled rows

  const int t = threadIdx.x;
  const int lane = t & 63, wv = t >> 6;
  const int bn = blockIdx.y;
  const int qb = bn >> 4, hn = bn & 15;
  const int c4 = lane & 15, g4 = lane >> 4;

  const char* Qwb = (const char*)(Qw + (size_t)bn * QL * 64);
  const char* Qrb = (const char*)(Qr + (size_t)bn * QL * 64);
  const char* Kbb = (const char*)(Kb + (size_t)bn * QL * 64);
  const char* Vtb = (const char*)(Vt + (size_t)bn * 64 * QL);
  const char* Rkb = (const char*)(Rk + (size_t)hn * QL * 64);

  int addrs[4];
#pragma unroll
  for (int reg = 0; reg < 4; reg++) {
    int rr = g4 * 4 + reg;
    addrs[reg] = ((lane & 48) | ((c4 + 15 - rr) & 15)) << 2;
  }

  const float SCALE2 = 0.125f * 1.44269504088896340736f;  // exp2 domain

#pragma unroll 1
  for (int ph = 0; ph < 2; ph++) {
    const int itile = (ph == 0) ? (31 - (int)blockIdx.x) : (int)blockIdx.x;
    const int i0 = itile * 64;
    const int iw = i0 + wv * 16;
    const int niter = itile + 1;

    bf16x8 qwf[2], qrf[2];
#pragma unroll
    for (int kk = 0; kk < 2; kk++) {
      qwf[kk] = *(const bf16x8*)(Qwb + (size_t)(iw + c4) * 128 + kk * 64 + g4 * 16);
      qrf[kk] = *(const bf16x8*)(Qrb + (size_t)(iw + c4) * 128 + kk * 64 + g4 * 16);
    }

    f32x4 o_acc[4] = {};
    float m_run[4], l_run[4];
#pragma unroll
    for (int r = 0; r < 4; r++) { m_run[r] = -3.0e38f; l_run[r] = 0.f; }

    auto stage = [&](int b, int j0) {
      const int T0 = j0 - i0 + (QL - 64);
#pragma unroll
      for (int p = 0; p < 2; p++) {
        int o = t * 16 + p * 4096;
        int row = o >> 7, ch16 = ((((o & 127) >> 4) ^ (row & 7)) << 4);
        gload_lds16(Kbb + (size_t)(j0 + row) * 128 + ch16, (char*)K_lds[b] + o);
        gload_lds16(Vtb + (size_t)row * (QL * 2) + (size_t)j0 * 2 + ch16, (char*)V_lds[b] + o);
      }
#pragma unroll
      for (int p = 0; p < 4; p++) {
        int o = t * 16 + p * 4096;
        int r = o >> 7;
        int srow = T0 + r; srow = srow > QL - 1 ? QL - 1 : srow;  // masked cells only
        int ch16 = ((((o & 127) >> 4) ^ (r & 7)) << 4);
        gload_lds16(Rkb + (size_t)srow * 128 + ch16, (char*)R_lds[b] + o);
      }
    };

    stage(0, 0);
    asm volatile("s_waitcnt vmcnt(0)" ::: "memory");
    __builtin_amdgcn_s_barrier();
    __builtin_amdgcn_sched_barrier(0);

    int cur = 0;
#pragma unroll 1
    for (int it = 0; it < niter; ++it) {
      const int j0 = it * 64;
      if (it + 1 < niter) stage(cur ^ 1, j0 + 64);

      f32x4 acc_s[4] = {};
      f32x4 acc_bd[5] = {};
      const int baseloc = 48 - wv * 16;
      __builtin_amdgcn_s_setprio(1);
#pragma unroll
      for (int kk = 0; kk < 2; kk++) {
        const int sw = (((kk * 4 + g4) ^ (c4 & 7)) << 4);
#pragma unroll
        for (int nf = 0; nf < 4; nf++) {
          bf16x8 bk = *(const bf16x8*)((const char*)K_lds[cur] + (nf * 16 + c4) * 128 + sw);
          acc_s[nf] = __builtin_amdgcn_mfma_f32_16x16x32_bf16(qwf[kk], bk, acc_s[nf], 0, 0, 0);
        }
#pragma unroll
        for (int tf = 0; tf < 5; tf++) {
          int oo = baseloc + tf * 16 + c4;  // oo&7 == c4&7
          bf16x8 br = *(const bf16x8*)((const char*)R_lds[cur] + oo * 128 + sw);
          acc_bd[tf] = __builtin_amdgcn_mfma_f32_16x16x32_bf16(qrf[kk], br, acc_bd[tf], 0, 0, 0);
        }
      }
      __builtin_amdgcn_s_setprio(0);

      uint32_t pk[4][4];
#pragma unroll
      for (int nf = 0; nf < 4; nf++)
#pragma unroll
        for (int reg = 0; reg < 4; reg++)
          asm("v_cvt_pk_bf16_f32 %0, %1, %2"
              : "=v"(pk[nf][reg])
              : "v"(acc_bd[nf][reg]), "v"(acc_bd[nf + 1][reg]));

      float sv[4][4];
      float rowmax[4] = {-3.0e38f, -3.0e38f, -3.0e38f, -3.0e38f};
#pragma unroll
      for (int nf = 0; nf < 4; nf++) {
#pragma unroll
        for (int reg = 0; reg < 4; reg++) {
          int rr = g4 * 4 + reg;
          int jg = j0 + nf * 16 + c4;
          int ig = iw + rr;
          uint32_t pulled = (uint32_t)__builtin_amdgcn_ds_bpermute(addrs[reg], (int)pk[nf][reg]);
          uint32_t bits = (c4 > rr) ? (pulled & 0xffff0000u) : (pulled << 16);
          float v = (acc_s[nf][reg] + __uint_as_float(bits)) * SCALE2;
          v = (jg <= ig) ? v : -3.0e38f;
          sv[nf][reg] = v;
          rowmax[reg] = fmaxf(rowmax[reg], v);
        }
      }
#pragma unroll
      for (int reg = 0; reg < 4; reg++) {
        float rm = rowmax[reg];
        rm = fmaxf(rm, __shfl_xor(rm, 1));
        rm = fmaxf(rm, __shfl_xor(rm, 2));
        rm = fmaxf(rm, __shfl_xor(rm, 4));
        rm = fmaxf(rm, __shfl_xor(rm, 8));
        float mnew = fmaxf(m_run[reg], rm);
        float alpha = __builtin_amdgcn_exp2f(m_run[reg] - mnew);
        float rsum = 0.f;
#pragma unroll
        for (int nf = 0; nf < 4; nf++) {
          float p = __builtin_amdgcn_exp2f(sv[nf][reg] - mnew);
          sv[nf][reg] = p;
          rsum += p;
        }
        rsum += __shfl_xor(rsum, 1);
        rsum += __shfl_xor(rsum, 2);
        rsum += __shfl_xor(rsum, 4);
        rsum += __shfl_xor(rsum, 8);
        l_run[reg] = l_run[reg] * alpha + rsum;
        m_run[reg] = mnew;
#pragma unroll
        for (int df = 0; df < 4; df++) o_acc[df][reg] *= alpha;
      }

      {
        char* pb = (char*)P_lds[wv];
#pragma unroll
        for (int nf = 0; nf < 4; nf++)
#pragma unroll
          for (int reg = 0; reg < 4; reg++) {
            int row = g4 * 4 + reg, col = nf * 16 + c4;
            int byt = row * 128 + ((((col >> 3) ^ (row & 7))) << 4) + (col & 7) * 2;
            *(ushort*)(pb + byt) = f2bf(sv[nf][reg]);
          }
      }
      __builtin_amdgcn_s_setprio(1);
#pragma unroll
      for (int kk = 0; kk < 2; kk++) {
        const char* pb = (const char*)P_lds[wv];
        bf16x8 pa = *(const bf16x8*)(pb + c4 * 128 + (((kk * 4 + g4) ^ (c4 & 7)) << 4));
        const int sw = (((kk * 4 + g4) ^ (c4 & 7)) << 4);
#pragma unroll
        for (int df = 0; df < 4; df++) {
          bf16x8 bv = *(const bf16x8*)((const char*)V_lds[cur] + (df * 16 + c4) * 128 + sw);
          o_acc[df] = __builtin_amdgcn_mfma_f32_16x16x32_bf16(pa, bv, o_acc[df], 0, 0, 0);
        }
      }
      __builtin_amdgcn_s_setprio(0);

      asm volatile("s_waitcnt vmcnt(0)" ::: "memory");
      __builtin_amdgcn_s_barrier();
      __builtin_amdgcn_sched_barrier(0);
      cur ^= 1;
    }

#pragma unroll
    for (int reg = 0; reg < 4; reg++) {
      float inv = 1.0f / l_run[reg];
      int ig = iw + g4 * 4 + reg;
      size_t grow = (size_t)(ig * 2 + qb) * 1024 + hn * 64;
#pragma unroll
      for (int df = 0; df < 4; df++)
        out[grow + df * 16 + c4] = f2bf(o_acc[df][reg] * inv);
    }
  }
}

// ---------------- residual + LayerNorm ----------------
template <bool WB>
__global__ __launch_bounds__(256) void ln_res(
    const float* __restrict__ xa, const float* __restrict__ xb,
    const float* __restrict__ g, const float* __restrict__ bt,
    float* __restrict__ of, ushort* __restrict__ ob) {
  __shared__ float red[8];
  const int row = blockIdx.x;
  const int t = threadIdx.x;
  const int lane = t & 63, wv = t >> 6;
  const float4 a = *(const float4*)(xa + (size_t)row * 1024 + t * 4);
  const float4 c = *(const float4*)(xb + (size_t)row * 1024 + t * 4);
  float x[4] = {a.x + c.x, a.y + c.y, a.z + c.z, a.w + c.w};
  float s = x[0] + x[1] + x[2] + x[3];
  for (int m = 1; m < 64; m <<= 1) s += __shfl_xor(s, m);
  if (lane == 0) red[wv] = s;
  __syncthreads();
  float mu = (red[0] + red[1] + red[2] + red[3]) * (1.f / 1024.f);
  float d[4];
  float ss = 0.f;
#pragma unroll
  for (int i = 0; i < 4; i++) { d[i] = x[i] - mu; ss += d[i] * d[i]; }
  for (int m = 1; m < 64; m <<= 1) ss += __shfl_xor(ss, m);
  if (lane == 0) red[4 + wv] = ss;
  __syncthreads();
  float var = (red[4] + red[5] + red[6] + red[7]) * (1.f / 1024.f);
  float rs = rsqrtf(var + 1e-5f);
  float4 gv = *(const float4*)(g + t * 4);
  float4 bv = *(const float4*)(bt + t * 4);
  float y[4] = {d[0] * rs * gv.x + bv.x, d[1] * rs * gv.y + bv.y,
                d[2] * rs * gv.z + bv.z, d[3] * rs * gv.w + bv.w};
  float4 yo = make_float4(y[0], y[1], y[2], y[3]);
  *(float4*)(of + (size_t)row * 1024 + t * 4) = yo;
  if (WB) {
    ushort4 u;
    u.x = f2bf(y[0]); u.y = f2bf(y[1]); u.z = f2bf(y[2]); u.w = f2bf(y[3]);
    *(ushort4*)(ob + (size_t)row * 1024 + t * 4) = u;
  }
}

// ---------------- host orchestration ----------------
extern "C" void kernel_launch(void* const* d_in, const int* in_sizes, int n_in,
                              void* d_out, int out_size, void* d_ws, size_t ws_size,
                              hipStream_t stream) {
  const float* dec_inp = (const float*)d_in[0];
  const float* r_in = (const float*)d_in[1];
  const float* rwb = (const float*)d_in[2];
  const float* rrb = (const float*)d_in[3];
  const float* qkv_w = (const float*)d_in[4];
  const float* rnet_w = (const float*)d_in[5];
  const float* o_w = (const float*)d_in[6];
  const float* ln_attn_g = (const float*)d_in[7];
  const float* ln_attn_b = (const float*)d_in[8];
  const float* w1 = (const float*)d_in[9];
  const float* b1 = (const float*)d_in[10];
  const float* w2 = (const float*)d_in[11];
  const float* b2 = (const float*)d_in[12];
  const float* ln_ff_g = (const float*)d_in[13];
  const float* ln_ff_b = (const float*)d_in[14];
  float* out = (float*)d_out;

  char* ws = (char*)d_ws;
  size_t off = 0;
  auto alloc = [&](size_t bytes) {
    char* p = ws + off;
    off += (bytes + 255) & ~(size_t)255;
    return p;
  };
  const int ROWS = QL * 2;
  ushort* qkvw_b = (ushort*)alloc((size_t)3072 * 1024 * 2);
  ushort* rnetw_b = (ushort*)alloc((size_t)1024 * 1024 * 2);
  ushort* ow_b = (ushort*)alloc((size_t)1024 * 1024 * 2);
  ushort* w1_b = (ushort*)alloc((size_t)4096 * 1024 * 2);
  ushort* w2_b = (ushort*)alloc((size_t)1024 * 4096 * 2);
  ushort* x_b = (ushort*)alloc((size_t)ROWS * 1024 * 2);
  ushort* r_b = (ushort*)alloc((size_t)QL * 1024 * 2);
  ushort* Qw = (ushort*)alloc((size_t)32 * QL * 64 * 2);
  ushort* Qr = (ushort*)alloc((size_t)32 * QL * 64 * 2);
  ushort* Kb = (ushort*)alloc((size_t)32 * QL * 64 * 2);
  ushort* Vt = (ushort*)alloc((size_t)32 * 64 * QL * 2);
  ushort* rk = (ushort*)alloc((size_t)16 * QL * 64 * 2);
  ushort* avec = (ushort*)alloc((size_t)ROWS * 1024 * 2);
  float* attn_out = (float*)alloc((size_t)ROWS * 1024 * 4);
  float* x1f = (float*)alloc((size_t)ROWS * 1024 * 4);
  ushort* x1b = (ushort*)alloc((size_t)ROWS * 1024 * 2);
  ushort* hidden = (ushort*)alloc((size_t)ROWS * 4096 * 2);
  float* core = (float*)alloc((size_t)ROWS * 1024 * 4);

  auto cvt = [&](const float* src, ushort* dst, int n) {
    int n4 = n / 4;
    cvt_bf16_k<<<n4 / 256, 256, 0, stream>>>(src, dst, n4);
  };
  cvt(qkv_w, qkvw_b, 3072 * 1024);
  cvt(rnet_w, rnetw_b, 1024 * 1024);
  cvt(o_w, ow_b, 1024 * 1024);
  cvt(w1, w1_b, 4096 * 1024);
  cvt(w2, w2_b, 1024 * 4096);
  cvt(dec_inp, x_b, ROWS * 1024);
  cvt(r_in, r_b, QL * 1024);

  gemm_nt<EPI_QKV><<<dim3(3072 / 128, ROWS / 128), 256, 0, stream>>>(
      x_b, qkvw_b, ROWS, 3072, 1024, nullptr, nullptr, nullptr, Qw, Qr, Kb, Vt, rwb, rrb);
  gemm_nt64<EPI_RK><<<dim3(1024 / 64, QL / 128), 256, 0, stream>>>(
      r_b, rnetw_b, QL, 1024, 1024, nullptr, rk, nullptr);
  flash_attn<<<dim3(16, 32), 256, 0, stream>>>(Qw, Qr, Kb, Vt, rk, avec);
  gemm_nt64<EPI_F32><<<dim3(1024 / 64, ROWS / 128), 256, 0, stream>>>(
      avec, ow_b, ROWS, 1024, 1024, attn_out, nullptr, nullptr);
  ln_res<true><<<ROWS, 256, 0, stream>>>(dec_inp, attn_out, ln_attn_g, ln_attn_b, x1f, x1b);
  gemm_nt<EPI_RELU_BF16><<<dim3(4096 / 128, ROWS / 128), 256, 0, stream>>>(
      x1b, w1_b, ROWS, 4096, 1024, nullptr, hidden, b1, nullptr, nullptr, nullptr, nullptr,
      nullptr, nullptr);
  gemm_nt64<EPI_BIAS_F32><<<dim3(1024 / 64, ROWS / 128), 256, 0, stream>>>(
      hidden, w2_b, ROWS, 1024, 4096, core, nullptr, b2);
  ln_res<false><<<ROWS, 256, 0, stream>>>(x1f, core, ln_ff_g, ln_ff_b, out, nullptr);
}

// Round 8
// 350.065 us; speedup vs baseline: 1.5188x; 1.0237x over previous
//
#include <hip/hip_runtime.h>
#include <stdint.h>

#define QL 2048
#define NHEAD 16
#define DHEAD 64
#define DMODEL 1024
#define DINNER 4096

typedef __attribute__((ext_vector_type(8))) short bf16x8;
typedef __attribute__((ext_vector_type(4))) float f32x4;

__device__ __forceinline__ ushort f2bf(float f) {
  uint32_t u = __float_as_uint(f);
  u = (u + 0x7fffu + ((u >> 16) & 1u)) >> 16;
  return (ushort)u;
}

__device__ __forceinline__ void gload_lds16(const void* g, void* l) {
  auto gp = reinterpret_cast<const uint32_t __attribute__((address_space(1)))*>(
      reinterpret_cast<uintptr_t>(g));
  auto lp = reinterpret_cast<uint32_t __attribute__((address_space(3)))*>(
      (uint32_t)reinterpret_cast<uintptr_t>(l));
  __builtin_amdgcn_global_load_lds(gp, lp, 16, 0, 0);
}

// ---------------- fused fp32 -> bf16 conversion (all 7 buffers, 1 launch) ----
struct CvtArgs {
  const float* src[7];
  ushort* dst[7];
  int end[7];  // cumulative float4 counts
};

__global__ __launch_bounds__(256) void cvt_all_k(CvtArgs a, int total4) {
  for (int i = blockIdx.x * 256 + threadIdx.x; i < total4; i += gridDim.x * 256) {
    int seg = 0;
#pragma unroll
    for (int s = 0; s < 6; s++)
      if (i >= a.end[s]) seg = s + 1;
    int base = seg ? a.end[seg - 1] : 0;
    int j = i - base;
    float4 v = ((const float4*)a.src[seg])[j];
    ushort4 u;
    u.x = f2bf(v.x); u.y = f2bf(v.y); u.z = f2bf(v.z); u.w = f2bf(v.w);
    ((ushort4*)a.dst[seg])[j] = u;
  }
}

// ---------------- NT GEMM: C[M,N] = A[M,K] * B[N,K]^T (bf16 in, f32 acc) ----
// 2-phase double-buffered: stage(next K-tile) BEFORE compute(cur); one
// vmcnt(0)+s_barrier after compute per iter.
#define EPI_QKV 0
#define EPI_RELU_BF16 3

template <int EPI>
__global__ __launch_bounds__(256) void gemm_nt(
    const ushort* __restrict__ A, const ushort* __restrict__ B, int M, int N, int K,
    float* __restrict__ Cf, ushort* __restrict__ Cb, const float* __restrict__ bias,
    ushort* __restrict__ qw, ushort* __restrict__ qr, ushort* __restrict__ kbuf,
    ushort* __restrict__ vt, const float* __restrict__ rwb, const float* __restrict__ rrb) {
  __shared__ ushort As[2][128 * 32];
  __shared__ ushort Bs[2][128 * 32];
  const int t = threadIdx.x;
  const int lane = t & 63, wv = t >> 6;
  const int wr = wv >> 1, wc = wv & 1;
  const int m0 = blockIdx.y * 128, n0 = blockIdx.x * 128;
  const int rif = lane & 15;
  const int kb = (lane >> 4) * 16;

  f32x4 acc[4][4] = {};
  const char* Ab = (const char*)A;
  const char* Bb = (const char*)B;
  const int arow = t >> 2;
  const int acol = (t & 3) * 16;

  auto stage = [&](int b, int k0) {
    size_t abase = ((size_t)(m0 + arow) * K + k0) * 2 + acol;
    gload_lds16(Ab + abase, (char*)As[b] + t * 16);
    gload_lds16(Ab + abase + (size_t)64 * K * 2, (char*)As[b] + t * 16 + 4096);
    size_t bbase = ((size_t)(n0 + arow) * K + k0) * 2 + acol;
    gload_lds16(Bb + bbase, (char*)Bs[b] + t * 16);
    gload_lds16(Bb + bbase + (size_t)64 * K * 2, (char*)Bs[b] + t * 16 + 4096);
  };

  stage(0, 0);
  asm volatile("s_waitcnt vmcnt(0)" ::: "memory");
  __builtin_amdgcn_s_barrier();
  __builtin_amdgcn_sched_barrier(0);

  int cur = 0;
#pragma unroll 1
  for (int k0 = 0; k0 < K; k0 += 32) {
    if (k0 + 32 < K) stage(cur ^ 1, k0 + 32);
    bf16x8 af[4], bfr[4];
#pragma unroll
    for (int m = 0; m < 4; m++)
      af[m] = *(const bf16x8*)((const char*)As[cur] + (wr * 64 + m * 16 + rif) * 64 + kb);
#pragma unroll
    for (int n = 0; n < 4; n++)
      bfr[n] = *(const bf16x8*)((const char*)Bs[cur] + (wc * 64 + n * 16 + rif) * 64 + kb);
    __builtin_amdgcn_s_setprio(1);
#pragma unroll
    for (int m = 0; m < 4; m++)
#pragma unroll
      for (int n = 0; n < 4; n++)
        acc[m][n] = __builtin_amdgcn_mfma_f32_16x16x32_bf16(af[m], bfr[n], acc[m][n], 0, 0, 0);
    __builtin_amdgcn_s_setprio(0);
    asm volatile("s_waitcnt vmcnt(0)" ::: "memory");
    __builtin_amdgcn_s_barrier();
    __builtin_amdgcn_sched_barrier(0);
    cur ^= 1;
  }

  const int rbase = (lane >> 4) * 4;
#pragma unroll
  for (int m = 0; m < 4; m++) {
#pragma unroll
    for (int n = 0; n < 4; n++) {
#pragma unroll
      for (int reg = 0; reg < 4; reg++) {
        int gr = m0 + wr * 64 + m * 16 + rbase + reg;
        int gc = n0 + wc * 64 + n * 16 + (lane & 15);
        float v = acc[m][n][reg];
        if (EPI == EPI_RELU_BF16) {
          Cb[(size_t)gr * N + gc] = f2bf(fmaxf(v + bias[gc], 0.f));
        } else {  // EPI_QKV
          int which = gc >> 10, hh = gc & 1023;
          int hn = hh >> 6, hd = hh & 63;
          int qi = gr >> 1, qb = gr & 1;
          size_t off = ((size_t)(qb * NHEAD + hn) * QL + qi) * 64 + hd;
          if (which == 0) {
            qw[off] = f2bf(v + rwb[hh]);
            qr[off] = f2bf(v + rrb[hh]);
          } else if (which == 1) {
            kbuf[off] = f2bf(v);
          } else {
            vt[((size_t)(qb * NHEAD + hn) * 64 + hd) * QL + qi] = f2bf(v);
          }
        }
      }
    }
  }
}

// ---- split-K BN=64 GEMM for N=1024 (o-proj, FFN2): blockIdx.z = K-half ----
// writes f32 partials to Cf0/Cf1 (disjoint -> deterministic); bias into z==0.
template <int WITH_BIAS>
__global__ __launch_bounds__(256) void gemm_nt64sk(
    const ushort* __restrict__ A, const ushort* __restrict__ B, int M, int N, int Kfull,
    int Klen, float* __restrict__ Cf0, float* __restrict__ Cf1,
    const float* __restrict__ bias) {
  __shared__ ushort As[2][128 * 32];
  __shared__ ushort Bs[2][64 * 32];
  const int t = threadIdx.x;
  const int lane = t & 63, wv = t >> 6;
  const int wr = wv >> 1, wc = wv & 1;
  const int m0 = blockIdx.y * 128, n0 = blockIdx.x * 64;
  const int z = blockIdx.z;
  const int koff = z * Klen;
  float* Cf = z ? Cf1 : Cf0;
  const int rif = lane & 15;
  const int kb = (lane >> 4) * 16;

  f32x4 acc[4][2] = {};
  const char* Ab = (const char*)A;
  const char* Bb = (const char*)B;
  const int arow = t >> 2;
  const int acol = (t & 3) * 16;

  auto stage = [&](int b, int k0) {
    size_t abase = ((size_t)(m0 + arow) * Kfull + koff + k0) * 2 + acol;
    gload_lds16(Ab + abase, (char*)As[b] + t * 16);
    gload_lds16(Ab + abase + (size_t)64 * Kfull * 2, (char*)As[b] + t * 16 + 4096);
    size_t bbase = ((size_t)(n0 + arow) * Kfull + koff + k0) * 2 + acol;
    gload_lds16(Bb + bbase, (char*)Bs[b] + t * 16);
  };

  stage(0, 0);
  asm volatile("s_waitcnt vmcnt(0)" ::: "memory");
  __builtin_amdgcn_s_barrier();
  __builtin_amdgcn_sched_barrier(0);

  int cur = 0;
#pragma unroll 1
  for (int k0 = 0; k0 < Klen; k0 += 32) {
    if (k0 + 32 < Klen) stage(cur ^ 1, k0 + 32);
    bf16x8 af[4], bfr[2];
#pragma unroll
    for (int m = 0; m < 4; m++)
      af[m] = *(const bf16x8*)((const char*)As[cur] + (wr * 64 + m * 16 + rif) * 64 + kb);
#pragma unroll
    for (int n = 0; n < 2; n++)
      bfr[n] = *(const bf16x8*)((const char*)Bs[cur] + (wc * 32 + n * 16 + rif) * 64 + kb);
    __builtin_amdgcn_s_setprio(1);
#pragma unroll
    for (int m = 0; m < 4; m++)
#pragma unroll
      for (int n = 0; n < 2; n++)
        acc[m][n] = __builtin_amdgcn_mfma_f32_16x16x32_bf16(af[m], bfr[n], acc[m][n], 0, 0, 0);
    __builtin_amdgcn_s_setprio(0);
    asm volatile("s_waitcnt vmcnt(0)" ::: "memory");
    __builtin_amdgcn_s_barrier();
    __builtin_amdgcn_sched_barrier(0);
    cur ^= 1;
  }

  const int rbase = (lane >> 4) * 4;
#pragma unroll
  for (int m = 0; m < 4; m++) {
#pragma unroll
    for (int n = 0; n < 2; n++) {
#pragma unroll
      for (int reg = 0; reg < 4; reg++) {
        int gr = m0 + wr * 64 + m * 16 + rbase + reg;
        int gc = n0 + wc * 32 + n * 16 + (lane & 15);
        float v = acc[m][n][reg];
        if (WITH_BIAS && z == 0) v += bias[gc];
        Cf[(size_t)gr * N + gc] = v;
      }
    }
  }
}

// ---- BM=64,BN=64 GEMM for rk (grid 512 instead of 256) ----
__global__ __launch_bounds__(256) void gemm_rk64(
    const ushort* __restrict__ A, const ushort* __restrict__ B, int M, int N, int K,
    ushort* __restrict__ Cb) {
  __shared__ ushort As[2][64 * 32];
  __shared__ ushort Bs[2][64 * 32];
  const int t = threadIdx.x;
  const int lane = t & 63, wv = t >> 6;
  const int wr = wv >> 1, wc = wv & 1;
  const int m0 = blockIdx.y * 64, n0 = blockIdx.x * 64;
  const int rif = lane & 15;
  const int kb = (lane >> 4) * 16;

  f32x4 acc[2][2] = {};
  const char* Ab = (const char*)A;
  const char* Bb = (const char*)B;
  const int arow = t >> 2;
  const int acol = (t & 3) * 16;

  auto stage = [&](int b, int k0) {
    size_t abase = ((size_t)(m0 + arow) * K + k0) * 2 + acol;
    gload_lds16(Ab + abase, (char*)As[b] + t * 16);
    size_t bbase = ((size_t)(n0 + arow) * K + k0) * 2 + acol;
    gload_lds16(Bb + bbase, (char*)Bs[b] + t * 16);
  };

  stage(0, 0);
  asm volatile("s_waitcnt vmcnt(0)" ::: "memory");
  __builtin_amdgcn_s_barrier();
  __builtin_amdgcn_sched_barrier(0);

  int cur = 0;
#pragma unroll 1
  for (int k0 = 0; k0 < K; k0 += 32) {
    if (k0 + 32 < K) stage(cur ^ 1, k0 + 32);
    bf16x8 af[2], bfr[2];
#pragma unroll
    for (int m = 0; m < 2; m++)
      af[m] = *(const bf16x8*)((const char*)As[cur] + (wr * 32 + m * 16 + rif) * 64 + kb);
#pragma unroll
    for (int n = 0; n < 2; n++)
      bfr[n] = *(const bf16x8*)((const char*)Bs[cur] + (wc * 32 + n * 16 + rif) * 64 + kb);
    __builtin_amdgcn_s_setprio(1);
#pragma unroll
    for (int m = 0; m < 2; m++)
#pragma unroll
      for (int n = 0; n < 2; n++)
        acc[m][n] = __builtin_amdgcn_mfma_f32_16x16x32_bf16(af[m], bfr[n], acc[m][n], 0, 0, 0);
    __builtin_amdgcn_s_setprio(0);
    asm volatile("s_waitcnt vmcnt(0)" ::: "memory");
    __builtin_amdgcn_s_barrier();
    __builtin_amdgcn_sched_barrier(0);
    cur ^= 1;
  }

  const int rbase = (lane >> 4) * 4;
#pragma unroll
  for (int m = 0; m < 2; m++) {
#pragma unroll
    for (int n = 0; n < 2; n++) {
#pragma unroll
      for (int reg = 0; reg < 4; reg++) {
        int gr = m0 + wr * 32 + m * 16 + rbase + reg;
        int gc = n0 + wc * 32 + n * 16 + (lane & 15);
        int hn = gc >> 6, hd = gc & 63;
        Cb[((size_t)hn * QL + gr) * 64 + hd] = f2bf(acc[m][n][reg]);
      }
    }
  }
}

// ---------------- fused causal attention with TXL rel-shift (unchanged) ----
__global__ __launch_bounds__(256) void flash_attn(
    const ushort* __restrict__ Qw, const ushort* __restrict__ Qr,
    const ushort* __restrict__ Kb, const ushort* __restrict__ Vt,
    const ushort* __restrict__ Rk, ushort* __restrict__ out) {
  __shared__ ushort K_lds[2][64 * 64];
  __shared__ ushort V_lds[2][64 * 64];   // [d][j], swizzled
  __shared__ ushort R_lds[2][128 * 64];  // rows T0..T0+127, swizzled
  __shared__ ushort P_lds[4][16 * 64];   // per-wave P, swizzled rows

  const int t = threadIdx.x;
  const int lane = t & 63, wv = t >> 6;
  const int bn = blockIdx.y;
  const int qb = bn >> 4, hn = bn & 15;
  const int c4 = lane & 15, g4 = lane >> 4;

  const char* Qwb = (const char*)(Qw + (size_t)bn * QL * 64);
  const char* Qrb = (const char*)(Qr + (size_t)bn * QL * 64);
  const char* Kbb = (const char*)(Kb + (size_t)bn * QL * 64);
  const char* Vtb = (const char*)(Vt + (size_t)bn * 64 * QL);
  const char* Rkb = (const char*)(Rk + (size_t)hn * QL * 64);

  int addrs[4];
#pragma unroll
  for (int reg = 0; reg < 4; reg++) {
    int rr = g4 * 4 + reg;
    addrs[reg] = ((lane & 48) | ((c4 + 15 - rr) & 15)) << 2;
  }

  const float SCALE2 = 0.125f * 1.44269504088896340736f;  // exp2 domain

#pragma unroll 1
  for (int ph = 0; ph < 2; ph++) {
    const int itile = (ph == 0) ? (31 - (int)blockIdx.x) : (int)blockIdx.x;
    const int i0 = itile * 64;
    const int iw = i0 + wv * 16;
    const int niter = itile + 1;

    bf16x8 qwf[2], qrf[2];
#pragma unroll
    for (int kk = 0; kk < 2; kk++) {
      qwf[kk] = *(const bf16x8*)(Qwb + (size_t)(iw + c4) * 128 + kk * 64 + g4 * 16);
      qrf[kk] = *(const bf16x8*)(Qrb + (size_t)(iw + c4) * 128 + kk * 64 + g4 * 16);
    }

    f32x4 o_acc[4] = {};
    float m_run[4], l_run[4];
#pragma unroll
    for (int r = 0; r < 4; r++) { m_run[r] = -3.0e38f; l_run[r] = 0.f; }

    auto stage = [&](int b, int j0) {
      const int T0 = j0 - i0 + (QL - 64);
#pragma unroll
      for (int p = 0; p < 2; p++) {
        int o = t * 16 + p * 4096;
        int row = o >> 7, ch16 = ((((o & 127) >> 4) ^ (row & 7)) << 4);
        gload_lds16(Kbb + (size_t)(j0 + row) * 128 + ch16, (char*)K_lds[b] + o);
        gload_lds16(Vtb + (size_t)row * (QL * 2) + (size_t)j0 * 2 + ch16, (char*)V_lds[b] + o);
      }
#pragma unroll
      for (int p = 0; p < 4; p++) {
        int o = t * 16 + p * 4096;
        int r = o >> 7;
        int srow = T0 + r; srow = srow > QL - 1 ? QL - 1 : srow;  // masked cells only
        int ch16 = ((((o & 127) >> 4) ^ (r & 7)) << 4);
        gload_lds16(Rkb + (size_t)srow * 128 + ch16, (char*)R_lds[b] + o);
      }
    };

    stage(0, 0);
    asm volatile("s_waitcnt vmcnt(0)" ::: "memory");
    __builtin_amdgcn_s_barrier();
    __builtin_amdgcn_sched_barrier(0);

    int cur = 0;
#pragma unroll 1
    for (int it = 0; it < niter; ++it) {
      const int j0 = it * 64;
      if (it + 1 < niter) stage(cur ^ 1, j0 + 64);

      f32x4 acc_s[4] = {};
      f32x4 acc_bd[5] = {};
      const int baseloc = 48 - wv * 16;
      __builtin_amdgcn_s_setprio(1);
#pragma unroll
      for (int kk = 0; kk < 2; kk++) {
        const int sw = (((kk * 4 + g4) ^ (c4 & 7)) << 4);
#pragma unroll
        for (int nf = 0; nf < 4; nf++) {
          bf16x8 bk = *(const bf16x8*)((const char*)K_lds[cur] + (nf * 16 + c4) * 128 + sw);
          acc_s[nf] = __builtin_amdgcn_mfma_f32_16x16x32_bf16(qwf[kk], bk, acc_s[nf], 0, 0, 0);
        }
#pragma unroll
        for (int tf = 0; tf < 5; tf++) {
          int oo = baseloc + tf * 16 + c4;  // oo&7 == c4&7
          bf16x8 br = *(const bf16x8*)((const char*)R_lds[cur] + oo * 128 + sw);
          acc_bd[tf] = __builtin_amdgcn_mfma_f32_16x16x32_bf16(qrf[kk], br, acc_bd[tf], 0, 0, 0);
        }
      }
      __builtin_amdgcn_s_setprio(0);

      uint32_t pk[4][4];
#pragma unroll
      for (int nf = 0; nf < 4; nf++)
#pragma unroll
        for (int reg = 0; reg < 4; reg++)
          asm("v_cvt_pk_bf16_f32 %0, %1, %2"
              : "=v"(pk[nf][reg])
              : "v"(acc_bd[nf][reg]), "v"(acc_bd[nf + 1][reg]));

      float sv[4][4];
      float rowmax[4] = {-3.0e38f, -3.0e38f, -3.0e38f, -3.0e38f};
#pragma unroll
      for (int nf = 0; nf < 4; nf++) {
#pragma unroll
        for (int reg = 0; reg < 4; reg++) {
          int rr = g4 * 4 + reg;
          int jg = j0 + nf * 16 + c4;
          int ig = iw + rr;
          uint32_t pulled = (uint32_t)__builtin_amdgcn_ds_bpermute(addrs[reg], (int)pk[nf][reg]);
          uint32_t bits = (c4 > rr) ? (pulled & 0xffff0000u) : (pulled << 16);
          float v = (acc_s[nf][reg] + __uint_as_float(bits)) * SCALE2;
          v = (jg <= ig) ? v : -3.0e38f;
          sv[nf][reg] = v;
          rowmax[reg] = fmaxf(rowmax[reg], v);
        }
      }
#pragma unroll
      for (int reg = 0; reg < 4; reg++) {
        float rm = rowmax[reg];
        rm = fmaxf(rm, __shfl_xor(rm, 1));
        rm = fmaxf(rm, __shfl_xor(rm, 2));
        rm = fmaxf(rm, __shfl_xor(rm, 4));
        rm = fmaxf(rm, __shfl_xor(rm, 8));
        float mnew = fmaxf(m_run[reg], rm);
        float alpha = __builtin_amdgcn_exp2f(m_run[reg] - mnew);
        float rsum = 0.f;
#pragma unroll
        for (int nf = 0; nf < 4; nf++) {
          float p = __builtin_amdgcn_exp2f(sv[nf][reg] - mnew);
          sv[nf][reg] = p;
          rsum += p;
        }
        rsum += __shfl_xor(rsum, 1);
        rsum += __shfl_xor(rsum, 2);
        rsum += __shfl_xor(rsum, 4);
        rsum += __shfl_xor(rsum, 8);
        l_run[reg] = l_run[reg] * alpha + rsum;
        m_run[reg] = mnew;
#pragma unroll
        for (int df = 0; df < 4; df++) o_acc[df][reg] *= alpha;
      }

      {
        char* pb = (char*)P_lds[wv];
#pragma unroll
        for (int nf = 0; nf < 4; nf++)
#pragma unroll
          for (int reg = 0; reg < 4; reg++) {
            int row = g4 * 4 + reg, col = nf * 16 + c4;
            int byt = row * 128 + ((((col >> 3) ^ (row & 7))) << 4) + (col & 7) * 2;
            *(ushort*)(pb + byt) = f2bf(sv[nf][reg]);
          }
      }
      __builtin_amdgcn_s_setprio(1);
#pragma unroll
      for (int kk = 0; kk < 2; kk++) {
        const char* pb = (const char*)P_lds[wv];
        bf16x8 pa = *(const bf16x8*)(pb + c4 * 128 + (((kk * 4 + g4) ^ (c4 & 7)) << 4));
        const int sw = (((kk * 4 + g4) ^ (c4 & 7)) << 4);
#pragma unroll
        for (int df = 0; df < 4; df++) {
          bf16x8 bv = *(const bf16x8*)((const char*)V_lds[cur] + (df * 16 + c4) * 128 + sw);
          o_acc[df] = __builtin_amdgcn_mfma_f32_16x16x32_bf16(pa, bv, o_acc[df], 0, 0, 0);
        }
      }
      __builtin_amdgcn_s_setprio(0);

      asm volatile("s_waitcnt vmcnt(0)" ::: "memory");
      __builtin_amdgcn_s_barrier();
      __builtin_amdgcn_sched_barrier(0);
      cur ^= 1;
    }

#pragma unroll
    for (int reg = 0; reg < 4; reg++) {
      float inv = 1.0f / l_run[reg];
      int ig = iw + g4 * 4 + reg;
      size_t grow = (size_t)(ig * 2 + qb) * 1024 + hn * 64;
#pragma unroll
      for (int df = 0; df < 4; df++)
        out[grow + df * 16 + c4] = f2bf(o_acc[df][reg] * inv);
    }
  }
}

// ---------------- residual + 2 partials + LayerNorm ----------------
template <bool WB>
__global__ __launch_bounds__(256) void ln_res3(
    const float* __restrict__ xa, const float* __restrict__ xb0,
    const float* __restrict__ xb1, const float* __restrict__ g,
    const float* __restrict__ bt, float* __restrict__ of, ushort* __restrict__ ob) {
  __shared__ float red[8];
  const int row = blockIdx.x;
  const int t = threadIdx.x;
  const int lane = t & 63, wv = t >> 6;
  const float4 a = *(const float4*)(xa + (size_t)row * 1024 + t * 4);
  const float4 c0 = *(const float4*)(xb0 + (size_t)row * 1024 + t * 4);
  const float4 c1 = *(const float4*)(xb1 + (size_t)row * 1024 + t * 4);
  float x[4] = {a.x + c0.x + c1.x, a.y + c0.y + c1.y, a.z + c0.z + c1.z, a.w + c0.w + c1.w};
  float s = x[0] + x[1] + x[2] + x[3];
  for (int m = 1; m < 64; m <<= 1) s += __shfl_xor(s, m);
  if (lane == 0) red[wv] = s;
  __syncthreads();
  float mu = (red[0] + red[1] + red[2] + red[3]) * (1.f / 1024.f);
  float d[4];
  float ss = 0.f;
#pragma unroll
  for (int i = 0; i < 4; i++) { d[i] = x[i] - mu; ss += d[i] * d[i]; }
  for (int m = 1; m < 64; m <<= 1) ss += __shfl_xor(ss, m);
  if (lane == 0) red[4 + wv] = ss;
  __syncthreads();
  float var = (red[4] + red[5] + red[6] + red[7]) * (1.f / 1024.f);
  float rs = rsqrtf(var + 1e-5f);
  float4 gv = *(const float4*)(g + t * 4);
  float4 bv = *(const float4*)(bt + t * 4);
  float y[4] = {d[0] * rs * gv.x + bv.x, d[1] * rs * gv.y + bv.y,
                d[2] * rs * gv.z + bv.z, d[3] * rs * gv.w + bv.w};
  float4 yo = make_float4(y[0], y[1], y[2], y[3]);
  *(float4*)(of + (size_t)row * 1024 + t * 4) = yo;
  if (WB) {
    ushort4 u;
    u.x = f2bf(y[0]); u.y = f2bf(y[1]); u.z = f2bf(y[2]); u.w = f2bf(y[3]);
    *(ushort4*)(ob + (size_t)row * 1024 + t * 4) = u;
  }
}

// ---------------- host orchestration ----------------
extern "C" void kernel_launch(void* const* d_in, const int* in_sizes, int n_in,
                              void* d_out, int out_size, void* d_ws, size_t ws_size,
                              hipStream_t stream) {
  const float* dec_inp = (const float*)d_in[0];
  const float* r_in = (const float*)d_in[1];
  const float* rwb = (const float*)d_in[2];
  const float* rrb = (const float*)d_in[3];
  const float* qkv_w = (const float*)d_in[4];
  const float* rnet_w = (const float*)d_in[5];
  const float* o_w = (const float*)d_in[6];
  const float* ln_attn_g = (const float*)d_in[7];
  const float* ln_attn_b = (const float*)d_in[8];
  const float* w1 = (const float*)d_in[9];
  const float* b1 = (const float*)d_in[10];
  const float* w2 = (const float*)d_in[11];
  const float* b2 = (const float*)d_in[12];
  const float* ln_ff_g = (const float*)d_in[13];
  const float* ln_ff_b = (const float*)d_in[14];
  float* out = (float*)d_out;

  char* ws = (char*)d_ws;
  size_t off = 0;
  auto alloc = [&](size_t bytes) {
    char* p = ws + off;
    off += (bytes + 255) & ~(size_t)255;
    return p;
  };
  const int ROWS = QL * 2;
  ushort* qkvw_b = (ushort*)alloc((size_t)3072 * 1024 * 2);
  ushort* rnetw_b = (ushort*)alloc((size_t)1024 * 1024 * 2);
  ushort* ow_b = (ushort*)alloc((size_t)1024 * 1024 * 2);
  ushort* w1_b = (ushort*)alloc((size_t)4096 * 1024 * 2);
  ushort* w2_b = (ushort*)alloc((size_t)1024 * 4096 * 2);
  ushort* x_b = (ushort*)alloc((size_t)ROWS * 1024 * 2);
  ushort* r_b = (ushort*)alloc((size_t)QL * 1024 * 2);
  ushort* Qw = (ushort*)alloc((size_t)32 * QL * 64 * 2);
  ushort* Qr = (ushort*)alloc((size_t)32 * QL * 64 * 2);
  ushort* Kb = (ushort*)alloc((size_t)32 * QL * 64 * 2);
  ushort* Vt = (ushort*)alloc((size_t)32 * 64 * QL * 2);
  ushort* rk = (ushort*)alloc((size_t)16 * QL * 64 * 2);
  ushort* avec = (ushort*)alloc((size_t)ROWS * 1024 * 2);
  float* p0 = (float*)alloc((size_t)ROWS * 1024 * 4);
  float* p1 = (float*)alloc((size_t)ROWS * 1024 * 4);
  float* x1f = (float*)alloc((size_t)ROWS * 1024 * 4);
  ushort* x1b = (ushort*)alloc((size_t)ROWS * 1024 * 2);
  ushort* hidden = (ushort*)alloc((size_t)ROWS * 4096 * 2);
  float* q0 = (float*)alloc((size_t)ROWS * 1024 * 4);
  float* q1 = (float*)alloc((size_t)ROWS * 1024 * 4);

  // one fused cvt launch for all 7 fp32->bf16 conversions
  CvtArgs ca;
  int n4[7] = {3072 * 1024 / 4, 1024 * 1024 / 4, 1024 * 1024 / 4, 4096 * 1024 / 4,
               1024 * 4096 / 4, ROWS * 1024 / 4, QL * 1024 / 4};
  const float* srcs[7] = {qkv_w, rnet_w, o_w, w1, w2, dec_inp, r_in};
  ushort* dsts[7] = {qkvw_b, rnetw_b, ow_b, w1_b, w2_b, x_b, r_b};
  int cum = 0;
  for (int i = 0; i < 7; i++) {
    ca.src[i] = srcs[i];
    ca.dst[i] = dsts[i];
    cum += n4[i];
    ca.end[i] = cum;
  }
  cvt_all_k<<<2048, 256, 0, stream>>>(ca, cum);

  gemm_nt<EPI_QKV><<<dim3(3072 / 128, ROWS / 128), 256, 0, stream>>>(
      x_b, qkvw_b, ROWS, 3072, 1024, nullptr, nullptr, nullptr, Qw, Qr, Kb, Vt, rwb, rrb);
  gemm_rk64<<<dim3(1024 / 64, QL / 64), 256, 0, stream>>>(r_b, rnetw_b, QL, 1024, 1024, rk);
  flash_attn<<<dim3(16, 32), 256, 0, stream>>>(Qw, Qr, Kb, Vt, rk, avec);
  // o-proj split-K=2 (K=512 each), partials p0/p1
  gemm_nt64sk<0><<<dim3(1024 / 64, ROWS / 128, 2), 256, 0, stream>>>(
      avec, ow_b, ROWS, 1024, 1024, 512, p0, p1, nullptr);
  ln_res3<true><<<ROWS, 256, 0, stream>>>(dec_inp, p0, p1, ln_attn_g, ln_attn_b, x1f, x1b);
  gemm_nt<EPI_RELU_BF16><<<dim3(4096 / 128, ROWS / 128), 256, 0, stream>>>(
      x1b, w1_b, ROWS, 4096, 1024, nullptr, hidden, b1, nullptr, nullptr, nullptr, nullptr,
      nullptr, nullptr);
  // FFN2 split-K=2 (K=2048 each), bias folded into z==0 partial
  gemm_nt64sk<1><<<dim3(1024 / 64, ROWS / 128, 2), 256, 0, stream>>>(
      hidden, w2_b, ROWS, 1024, 4096, 2048, q0, q1, b2);
  ln_res3<false><<<ROWS, 256, 0, stream>>>(x1f, q0, q1, ln_ff_g, ln_ff_b, out, nullptr);
}